// Round 1
// baseline (943.773 us; speedup 1.0000x reference)
//
#include <hip/hip_runtime.h>

// GAT 3-layer, N=100000 nodes, E=1.6M edges (+N self loops), Fin=64, H=128.
// Strategy: per-call CSR build (by dst), then per layer:
//   gemm (h = x@W, fused alpha_s/alpha_d epilogue) -> per-node wave softmax+aggregate.
// All fp32. No float atomics in hot path (CSR aggregation in registers).

#define NN 100000
#define NE 1600000
#define ET (NE + NN)   // edges + self loops
#define HD 128

// ---------------- CSR build ----------------

__global__ __launch_bounds__(256) void count_kernel(const int* __restrict__ ei,
                                                    int* __restrict__ deg) {
    int e = blockIdx.x * 256 + threadIdx.x;
    if (e < NE) atomicAdd(&deg[ei[NE + e]], 1);
}

__global__ __launch_bounds__(1024) void scan1_kernel(const int* __restrict__ deg,
                                                     int* __restrict__ rowptr,
                                                     int* __restrict__ partials) {
    __shared__ int s[1024];
    int t = threadIdx.x;
    int i = blockIdx.x * 1024 + t;
    int v = (i < NN) ? (deg[i] + 1) : 0;   // +1 = self loop
    s[t] = v;
    __syncthreads();
    #pragma unroll
    for (int off = 1; off < 1024; off <<= 1) {
        int add = (t >= off) ? s[t - off] : 0;
        __syncthreads();
        s[t] += add;
        __syncthreads();
    }
    if (i < NN) rowptr[i + 1] = s[t];            // block-local inclusive scan
    if (t == 1023) partials[blockIdx.x] = s[t];  // block total
}

__global__ void scan2_kernel(int* __restrict__ partials, int nb) {
    __shared__ int s[128];
    int t = threadIdx.x;
    int v = (t < nb) ? partials[t] : 0;
    s[t] = v;
    __syncthreads();
    #pragma unroll
    for (int off = 1; off < 128; off <<= 1) {
        int add = (t >= off) ? s[t - off] : 0;
        __syncthreads();
        s[t] += add;
        __syncthreads();
    }
    if (t < nb) partials[t] = s[t] - v;  // exclusive offsets
}

__global__ __launch_bounds__(1024) void scan3_kernel(int* __restrict__ rowptr,
                                                     int* __restrict__ cursor,
                                                     const int* __restrict__ partials) {
    int t = threadIdx.x;
    int i = blockIdx.x * 1024 + t;
    if (i < NN) {
        int val = rowptr[i + 1] + partials[blockIdx.x];
        rowptr[i + 1] = val;
        if (i + 1 < NN) cursor[i + 1] = val;
        if (i == 0) { rowptr[0] = 0; cursor[0] = 0; }
    }
}

__global__ __launch_bounds__(256) void scatter_kernel(const int* __restrict__ ei,
                                                      int* __restrict__ cursor,
                                                      int* __restrict__ col) {
    int e = blockIdx.x * 256 + threadIdx.x;
    if (e >= ET) return;
    int s, d;
    if (e < NE) { s = ei[e]; d = ei[NE + e]; }
    else        { s = d = e - NE; }          // self loop
    int pos = atomicAdd(&cursor[d], 1);
    col[pos] = s;                            // store SRC node id directly
}

// ---------------- GEMM: Hout = X @ W, plus alpha_s/alpha_d epilogue ----------------
// 256 threads; block computes 64 rows x 128 cols. tc = t&31 -> 4-col group, tr = t>>5 -> 8-row group.

template <int K>
__global__ __launch_bounds__(256) void gemm_kernel(const float* __restrict__ X,
                                                   const float* __restrict__ W,
                                                   const float* __restrict__ a_src,
                                                   const float* __restrict__ a_dst,
                                                   float* __restrict__ Hout,
                                                   float* __restrict__ As,
                                                   float* __restrict__ Ad) {
    __shared__ float sW[64 * 128];  // 32 KB  (K-tile of W)
    __shared__ float sX[64 * 64];   // 16 KB  (64 rows x 64 ks)
    const int t = threadIdx.x;
    const int tc = t & 31;
    const int tr = t >> 5;
    const int row0 = blockIdx.x * 64;

    float acc[8][4];
    #pragma unroll
    for (int r = 0; r < 8; ++r) { acc[r][0] = acc[r][1] = acc[r][2] = acc[r][3] = 0.f; }

    for (int kt = 0; kt < K; kt += 64) {
        // stage W[kt..kt+64)[128] (8192 floats)
        const float4* Wv = (const float4*)(W + kt * 128);
        float4* sWv = (float4*)sW;
        #pragma unroll
        for (int i = 0; i < 8; ++i) sWv[t + i * 256] = Wv[t + i * 256];
        // stage X[row0..row0+64)[kt..kt+64) (4096 floats)
        float4* sXv = (float4*)sX;
        #pragma unroll
        for (int i = 0; i < 4; ++i) {
            int idx = t + i * 256;   // 0..1023
            int r = idx >> 4;
            int j = idx & 15;
            int gr = row0 + r; if (gr >= NN) gr = NN - 1;
            sXv[idx] = *(const float4*)&X[gr * K + kt + j * 4];
        }
        __syncthreads();

        #pragma unroll 4
        for (int k4 = 0; k4 < 64; k4 += 4) {
            float4 wv[4];
            #pragma unroll
            for (int kk = 0; kk < 4; ++kk)
                wv[kk] = *(const float4*)&sW[(k4 + kk) * 128 + tc * 4];
            #pragma unroll
            for (int r = 0; r < 8; ++r) {
                float4 xv = *(const float4*)&sX[(tr * 8 + r) * 64 + k4];
                float xs[4] = {xv.x, xv.y, xv.z, xv.w};
                #pragma unroll
                for (int kk = 0; kk < 4; ++kk) {
                    acc[r][0] = fmaf(xs[kk], wv[kk].x, acc[r][0]);
                    acc[r][1] = fmaf(xs[kk], wv[kk].y, acc[r][1]);
                    acc[r][2] = fmaf(xs[kk], wv[kk].z, acc[r][2]);
                    acc[r][3] = fmaf(xs[kk], wv[kk].w, acc[r][3]);
                }
            }
        }
        __syncthreads();
    }

    // store h
    #pragma unroll
    for (int r = 0; r < 8; ++r) {
        int gr = row0 + tr * 8 + r;
        if (gr < NN) {
            float4 o = {acc[r][0], acc[r][1], acc[r][2], acc[r][3]};
            *(float4*)&Hout[gr * HD + tc * 4] = o;
        }
    }
    // fused alpha_s / alpha_d (per-row dot over 128 cols; cols live in 32 lanes)
    float4 avs = *(const float4*)&a_src[tc * 4];
    float4 avd = *(const float4*)&a_dst[tc * 4];
    #pragma unroll
    for (int r = 0; r < 8; ++r) {
        float ps = acc[r][0] * avs.x + acc[r][1] * avs.y + acc[r][2] * avs.z + acc[r][3] * avs.w;
        float pd = acc[r][0] * avd.x + acc[r][1] * avd.y + acc[r][2] * avd.z + acc[r][3] * avd.w;
        #pragma unroll
        for (int m = 16; m >= 1; m >>= 1) {
            ps += __shfl_xor(ps, m);
            pd += __shfl_xor(pd, m);
        }
        if (tc == 0) {
            int gr = row0 + tr * 8 + r;
            if (gr < NN) { As[gr] = ps; Ad[gr] = pd; }
        }
    }
}

// ---------------- per-dst softmax + aggregate: 1 wave per node ----------------

__global__ __launch_bounds__(256) void aggregate_kernel(const float* __restrict__ h,
                                                        const float* __restrict__ As,
                                                        const float* __restrict__ Ad,
                                                        const int* __restrict__ rowptr,
                                                        const int* __restrict__ col,
                                                        const float* __restrict__ bias,
                                                        float* __restrict__ out,
                                                        int relu) {
    const int lane = threadIdx.x & 63;
    const int node = blockIdx.x * 4 + (threadIdx.x >> 6);
    if (node >= NN) return;
    const int start = rowptr[node];
    const int end = rowptr[node + 1];
    const float ad_i = Ad[node];

    // pass 1: segment max (lanes stride edges)
    float m = -1e30f;
    for (int j = start + lane; j < end; j += 64) {
        float e = As[col[j]] + ad_i;
        e = (e > 0.f) ? e : 0.2f * e;
        m = fmaxf(m, e);
    }
    #pragma unroll
    for (int off = 32; off >= 1; off >>= 1) m = fmaxf(m, __shfl_xor(m, off));

    // pass 2: exp-weighted accumulate (wave walks edges serially; lane = 2 features)
    float denom = 0.f, ax = 0.f, ay = 0.f;
    for (int j = start; j < end; ++j) {
        int s = col[j];                       // wave-uniform
        float e = As[s] + ad_i;
        e = (e > 0.f) ? e : 0.2f * e;
        float w = __expf(e - m);
        denom += w;
        float2 hv = *(const float2*)&h[s * HD + lane * 2];
        ax = fmaf(w, hv.x, ax);
        ay = fmaf(w, hv.y, ay);
    }
    float inv = 1.0f / denom;
    float2 bv = *(const float2*)&bias[lane * 2];
    float ox = ax * inv + bv.x;
    float oy = ay * inv + bv.y;
    if (relu) { ox = fmaxf(ox, 0.f); oy = fmaxf(oy, 0.f); }
    float2 o = {ox, oy};
    *(float2*)&out[node * HD + lane * 2] = o;
}

// ---------------- readout ----------------

__global__ __launch_bounds__(256) void sum_kernel(const float* __restrict__ h,
                                                  float* __restrict__ g) {
    int t = threadIdx.x;
    int wave = t >> 6, lane = t & 63;
    float sx = 0.f, sy = 0.f;
    for (int r = blockIdx.x * 4 + wave; r < NN; r += gridDim.x * 4) {
        float2 v = *(const float2*)&h[r * HD + lane * 2];
        sx += v.x; sy += v.y;
    }
    __shared__ float sm[512];
    sm[wave * 128 + lane * 2]     = sx;
    sm[wave * 128 + lane * 2 + 1] = sy;
    __syncthreads();
    if (t < 128) {
        float s = sm[t] + sm[128 + t] + sm[256 + t] + sm[384 + t];
        atomicAdd(&g[t], s);
    }
}

__global__ void finalize_kernel(const float* __restrict__ g, const float* __restrict__ Wp,
                                const float* __restrict__ bp, float* __restrict__ out) {
    int t = threadIdx.x;
    float v = g[t] * Wp[t];
    #pragma unroll
    for (int m = 32; m >= 1; m >>= 1) v += __shfl_xor(v, m);
    __shared__ float red[2];
    if ((t & 63) == 0) red[t >> 6] = v;
    __syncthreads();
    if (t == 0) out[0] = (red[0] + red[1]) * (1.0f / NN) + bp[0];
}

// ---------------- launch ----------------

extern "C" void kernel_launch(void* const* d_in, const int* in_sizes, int n_in,
                              void* d_out, int out_size, void* d_ws, size_t ws_size,
                              hipStream_t stream) {
    const float* x   = (const float*)d_in[0];
    const int*   ei  = (const int*)d_in[1];
    const float* W0  = (const float*)d_in[2];
    const float* W1  = (const float*)d_in[3];
    const float* W2  = (const float*)d_in[4];
    const float* as0 = (const float*)d_in[5];
    const float* as1 = (const float*)d_in[6];
    const float* as2 = (const float*)d_in[7];
    const float* ad0 = (const float*)d_in[8];
    const float* ad1 = (const float*)d_in[9];
    const float* ad2 = (const float*)d_in[10];
    const float* b0  = (const float*)d_in[11];
    const float* b1  = (const float*)d_in[12];
    const float* b2  = (const float*)d_in[13];
    const float* Wp  = (const float*)d_in[14];
    const float* bp  = (const float*)d_in[15];
    float* out = (float*)d_out;

    char* p = (char*)d_ws;
    auto alloc = [&](size_t bytes) {
        char* r = p;
        p += (bytes + 255) & ~(size_t)255;
        return r;
    };
    float* hA      = (float*)alloc((size_t)NN * HD * 4);
    float* hB      = (float*)alloc((size_t)NN * HD * 4);
    float* As      = (float*)alloc((size_t)NN * 4);
    float* Ad      = (float*)alloc((size_t)NN * 4);
    int*   rowptr  = (int*)alloc((size_t)(NN + 1) * 4);
    int*   cursor  = (int*)alloc((size_t)NN * 4);
    int*   deg     = (int*)alloc((size_t)NN * 4);
    int*   col     = (int*)alloc((size_t)ET * 4);
    int*   partials= (int*)alloc(1024 * 4);
    float* g       = (float*)alloc(512);

    // CSR build
    hipMemsetAsync(deg, 0, NN * 4, stream);
    count_kernel<<<(NE + 255) / 256, 256, 0, stream>>>(ei, deg);
    const int SB = (NN + 1023) / 1024;  // 98
    scan1_kernel<<<SB, 1024, 0, stream>>>(deg, rowptr, partials);
    scan2_kernel<<<1, 128, 0, stream>>>(partials, SB);
    scan3_kernel<<<SB, 1024, 0, stream>>>(rowptr, cursor, partials);
    scatter_kernel<<<(ET + 255) / 256, 256, 0, stream>>>(ei, cursor, col);

    const int GB = (NN + 63) / 64;  // 1563
    const int AB = (NN + 3) / 4;    // 25000

    // layer 0
    gemm_kernel<64><<<GB, 256, 0, stream>>>(x, W0, as0, ad0, hA, As, Ad);
    aggregate_kernel<<<AB, 256, 0, stream>>>(hA, As, Ad, rowptr, col, b0, hB, 1);
    // layer 1
    gemm_kernel<128><<<GB, 256, 0, stream>>>(hB, W1, as1, ad1, hA, As, Ad);
    aggregate_kernel<<<AB, 256, 0, stream>>>(hA, As, Ad, rowptr, col, b1, hB, 1);
    // layer 2
    gemm_kernel<128><<<GB, 256, 0, stream>>>(hB, W2, as2, ad2, hA, As, Ad);
    aggregate_kernel<<<AB, 256, 0, stream>>>(hA, As, Ad, rowptr, col, b2, hB, 0);

    // readout
    hipMemsetAsync(g, 0, 128 * 4, stream);
    sum_kernel<<<256, 256, 0, stream>>>(hB, g);
    finalize_kernel<<<1, 128, 0, stream>>>(g, Wp, bp, out);
}

// Round 2
// 741.351 us; speedup vs baseline: 1.2730x; 1.2730x over previous
//
#include <hip/hip_runtime.h>

// GAT 3-layer, N=100000 nodes, E=1.6M edges (+N self loops), Fin=64, H=128.
// Per-call CSR build (by dst); per layer: fp32 GEMM with fused alpha epilogue
// (h stored as bf16 for the gather), then per-node wave online-softmax aggregate.

#define NN 100000
#define NE 1600000
#define ET (NE + NN)   // edges + self loops
#define HD 128

typedef unsigned int uint;
typedef unsigned short ushort;

__device__ __forceinline__ ushort f2b(float f) {   // fp32 -> bf16 RTN-even
    uint u = __float_as_uint(f);
    return (ushort)((u + 0x7fffu + ((u >> 16) & 1u)) >> 16);
}

// ---------------- CSR build ----------------

__global__ __launch_bounds__(256) void count_kernel(const int* __restrict__ ei,
                                                    int* __restrict__ deg) {
    int e = blockIdx.x * 256 + threadIdx.x;
    if (e < NE) atomicAdd(&deg[ei[NE + e]], 1);
}

__global__ __launch_bounds__(1024) void scan1_kernel(const int* __restrict__ deg,
                                                     int* __restrict__ rowptr,
                                                     int* __restrict__ partials) {
    __shared__ int s[1024];
    int t = threadIdx.x;
    int i = blockIdx.x * 1024 + t;
    int v = (i < NN) ? (deg[i] + 1) : 0;   // +1 = self loop
    s[t] = v;
    __syncthreads();
    #pragma unroll
    for (int off = 1; off < 1024; off <<= 1) {
        int add = (t >= off) ? s[t - off] : 0;
        __syncthreads();
        s[t] += add;
        __syncthreads();
    }
    if (i < NN) rowptr[i + 1] = s[t];            // block-local inclusive scan
    if (t == 1023) partials[blockIdx.x] = s[t];  // block total
}

__global__ void scan2_kernel(int* __restrict__ partials, int nb) {
    __shared__ int s[128];
    int t = threadIdx.x;
    int v = (t < nb) ? partials[t] : 0;
    s[t] = v;
    __syncthreads();
    #pragma unroll
    for (int off = 1; off < 128; off <<= 1) {
        int add = (t >= off) ? s[t - off] : 0;
        __syncthreads();
        s[t] += add;
        __syncthreads();
    }
    if (t < nb) partials[t] = s[t] - v;  // exclusive offsets
}

__global__ __launch_bounds__(1024) void scan3_kernel(int* __restrict__ rowptr,
                                                     int* __restrict__ cursor,
                                                     const int* __restrict__ partials) {
    int t = threadIdx.x;
    int i = blockIdx.x * 1024 + t;
    if (i < NN) {
        int val = rowptr[i + 1] + partials[blockIdx.x];
        rowptr[i + 1] = val;
        if (i + 1 < NN) cursor[i + 1] = val;
        if (i == 0) { rowptr[0] = 0; cursor[0] = 0; }
    }
}

__global__ __launch_bounds__(256) void scatter_kernel(const int* __restrict__ ei,
                                                      int* __restrict__ cursor,
                                                      int* __restrict__ col) {
    int e = blockIdx.x * 256 + threadIdx.x;
    if (e >= ET) return;
    int s, d;
    if (e < NE) { s = ei[e]; d = ei[NE + e]; }
    else        { s = d = e - NE; }          // self loop
    int pos = atomicAdd(&cursor[d], 1);
    col[pos] = s;                            // store SRC node id directly
}

// ---------------- GEMM: Hbf = bf16(X @ W), plus fp32 alpha_s/alpha_d epilogue ----------------
// 256 threads; block computes 64 rows x 128 cols. tc = t&31 -> 4-col group, tr = t>>5 -> 8-row group.

template <int K>
__global__ __launch_bounds__(256) void gemm_kernel(const float* __restrict__ X,
                                                   const float* __restrict__ W,
                                                   const float* __restrict__ a_src,
                                                   const float* __restrict__ a_dst,
                                                   ushort* __restrict__ Hbf,
                                                   float* __restrict__ As,
                                                   float* __restrict__ Ad) {
    __shared__ float sW[64 * 128];  // 32 KB  (K-tile of W)
    __shared__ float sX[64 * 64];   // 16 KB  (64 rows x 64 ks)
    const int t = threadIdx.x;
    const int tc = t & 31;
    const int tr = t >> 5;
    const int row0 = blockIdx.x * 64;

    float acc[8][4];
    #pragma unroll
    for (int r = 0; r < 8; ++r) { acc[r][0] = acc[r][1] = acc[r][2] = acc[r][3] = 0.f; }

    for (int kt = 0; kt < K; kt += 64) {
        const float4* Wv = (const float4*)(W + kt * 128);
        float4* sWv = (float4*)sW;
        #pragma unroll
        for (int i = 0; i < 8; ++i) sWv[t + i * 256] = Wv[t + i * 256];
        float4* sXv = (float4*)sX;
        #pragma unroll
        for (int i = 0; i < 4; ++i) {
            int idx = t + i * 256;   // 0..1023
            int r = idx >> 4;
            int j = idx & 15;
            int gr = row0 + r; if (gr >= NN) gr = NN - 1;
            sXv[idx] = *(const float4*)&X[gr * K + kt + j * 4];
        }
        __syncthreads();

        #pragma unroll 4
        for (int k4 = 0; k4 < 64; k4 += 4) {
            float4 wv[4];
            #pragma unroll
            for (int kk = 0; kk < 4; ++kk)
                wv[kk] = *(const float4*)&sW[(k4 + kk) * 128 + tc * 4];
            #pragma unroll
            for (int r = 0; r < 8; ++r) {
                float4 xv = *(const float4*)&sX[(tr * 8 + r) * 64 + k4];
                float xs[4] = {xv.x, xv.y, xv.z, xv.w};
                #pragma unroll
                for (int kk = 0; kk < 4; ++kk) {
                    acc[r][0] = fmaf(xs[kk], wv[kk].x, acc[r][0]);
                    acc[r][1] = fmaf(xs[kk], wv[kk].y, acc[r][1]);
                    acc[r][2] = fmaf(xs[kk], wv[kk].z, acc[r][2]);
                    acc[r][3] = fmaf(xs[kk], wv[kk].w, acc[r][3]);
                }
            }
        }
        __syncthreads();
    }

    // store h as bf16 (gather-side representation)
    #pragma unroll
    for (int r = 0; r < 8; ++r) {
        int gr = row0 + tr * 8 + r;
        if (gr < NN) {
            ushort4 o = {f2b(acc[r][0]), f2b(acc[r][1]), f2b(acc[r][2]), f2b(acc[r][3])};
            *(ushort4*)&Hbf[(size_t)gr * HD + tc * 4] = o;
        }
    }
    // fused alpha_s / alpha_d from fp32 accumulators
    float4 avs = *(const float4*)&a_src[tc * 4];
    float4 avd = *(const float4*)&a_dst[tc * 4];
    #pragma unroll
    for (int r = 0; r < 8; ++r) {
        float ps = acc[r][0] * avs.x + acc[r][1] * avs.y + acc[r][2] * avs.z + acc[r][3] * avs.w;
        float pd = acc[r][0] * avd.x + acc[r][1] * avd.y + acc[r][2] * avd.z + acc[r][3] * avd.w;
        #pragma unroll
        for (int m = 16; m >= 1; m >>= 1) {
            ps += __shfl_xor(ps, m);
            pd += __shfl_xor(pd, m);
        }
        if (tc == 0) {
            int gr = row0 + tr * 8 + r;
            if (gr < NN) { As[gr] = ps; Ad[gr] = pd; }
        }
    }
}

// ---------------- per-dst online softmax + aggregate: 1 wave per node ----------------
// Chunked: 64 edges get their col/As loads + e + w computed lane-parallel; the
// serial loop per edge is 2 shuffles + one 4B/lane bf16x2 row load + 2 FMA.

__global__ __launch_bounds__(256) void aggregate_kernel(const ushort* __restrict__ h,
                                                        const float* __restrict__ As,
                                                        const float* __restrict__ Ad,
                                                        const int* __restrict__ rowptr,
                                                        const int* __restrict__ col,
                                                        const float* __restrict__ bias,
                                                        float* __restrict__ out,
                                                        int relu) {
    const int lane = threadIdx.x & 63;
    const int node = blockIdx.x * 4 + (threadIdx.x >> 6);
    if (node >= NN) return;
    const int start = rowptr[node];
    const int end   = rowptr[node + 1];
    const float ad_i = Ad[node];

    float m = -1e30f;     // running max (wave-uniform)
    float denom_l = 0.f;  // per-lane partial softmax denominator
    float ax = 0.f, ay = 0.f;

    for (int base = start; base < end; base += 64) {
        const int cnt = min(64, end - base);
        int   sc = 0;
        float e  = -1e30f;
        if (lane < cnt) {
            sc = col[base + lane];
            float a = As[sc] + ad_i;
            e = (a > 0.f) ? a : 0.2f * a;       // leaky_relu 0.2
        }
        float cmax = e;
        #pragma unroll
        for (int off = 32; off >= 1; off >>= 1) cmax = fmaxf(cmax, __shfl_xor(cmax, off));
        if (cmax > m) {                          // uniform online rescale
            float s = __expf(m - cmax);          // 0 on first chunk
            ax *= s; ay *= s; denom_l *= s;
            m = cmax;
        }
        float w = (lane < cnt) ? __expf(e - m) : 0.f;
        denom_l += w;

        #pragma unroll 4
        for (int jj = 0; jj < cnt; ++jj) {
            int   s_j = __shfl(sc, jj);
            float w_j = __shfl(w, jj);
            uint v = *(const uint*)(h + (size_t)s_j * HD + lane * 2);
            float hx = __uint_as_float(v << 16);
            float hy = __uint_as_float(v & 0xffff0000u);
            ax = fmaf(w_j, hx, ax);
            ay = fmaf(w_j, hy, ay);
        }
    }

    #pragma unroll
    for (int off = 32; off >= 1; off >>= 1) denom_l += __shfl_xor(denom_l, off);
    float inv = 1.0f / denom_l;
    float2 bv = *(const float2*)&bias[lane * 2];
    float ox = ax * inv + bv.x;
    float oy = ay * inv + bv.y;
    if (relu) { ox = fmaxf(ox, 0.f); oy = fmaxf(oy, 0.f); }
    float2 o = {ox, oy};
    *(float2*)&out[(size_t)node * HD + lane * 2] = o;
}

// ---------------- readout ----------------

__global__ __launch_bounds__(256) void sum_kernel(const float* __restrict__ h,
                                                  float* __restrict__ g) {
    int t = threadIdx.x;
    int wave = t >> 6, lane = t & 63;
    float sx = 0.f, sy = 0.f;
    for (int r = blockIdx.x * 4 + wave; r < NN; r += gridDim.x * 4) {
        float2 v = *(const float2*)&h[(size_t)r * HD + lane * 2];
        sx += v.x; sy += v.y;
    }
    __shared__ float sm[512];
    sm[wave * 128 + lane * 2]     = sx;
    sm[wave * 128 + lane * 2 + 1] = sy;
    __syncthreads();
    if (t < 128) {
        float s = sm[t] + sm[128 + t] + sm[256 + t] + sm[384 + t];
        atomicAdd(&g[t], s);
    }
}

__global__ void finalize_kernel(const float* __restrict__ g, const float* __restrict__ Wp,
                                const float* __restrict__ bp, float* __restrict__ out) {
    int t = threadIdx.x;
    float v = g[t] * Wp[t];
    #pragma unroll
    for (int m = 32; m >= 1; m >>= 1) v += __shfl_xor(v, m);
    __shared__ float red[2];
    if ((t & 63) == 0) red[t >> 6] = v;
    __syncthreads();
    if (t == 0) out[0] = (red[0] + red[1]) * (1.0f / NN) + bp[0];
}

// ---------------- launch ----------------

extern "C" void kernel_launch(void* const* d_in, const int* in_sizes, int n_in,
                              void* d_out, int out_size, void* d_ws, size_t ws_size,
                              hipStream_t stream) {
    const float* x   = (const float*)d_in[0];
    const int*   ei  = (const int*)d_in[1];
    const float* W0  = (const float*)d_in[2];
    const float* W1  = (const float*)d_in[3];
    const float* W2  = (const float*)d_in[4];
    const float* as0 = (const float*)d_in[5];
    const float* as1 = (const float*)d_in[6];
    const float* as2 = (const float*)d_in[7];
    const float* ad0 = (const float*)d_in[8];
    const float* ad1 = (const float*)d_in[9];
    const float* ad2 = (const float*)d_in[10];
    const float* b0  = (const float*)d_in[11];
    const float* b1  = (const float*)d_in[12];
    const float* b2  = (const float*)d_in[13];
    const float* Wp  = (const float*)d_in[14];
    const float* bp  = (const float*)d_in[15];
    float* out = (float*)d_out;

    char* p = (char*)d_ws;
    auto alloc = [&](size_t bytes) {
        char* r = p;
        p += (bytes + 255) & ~(size_t)255;
        return r;
    };
    ushort* hbf    = (ushort*)alloc((size_t)NN * HD * 2);  // bf16 gather rows
    float* hF      = (float*)alloc((size_t)NN * HD * 4);   // fp32 layer output
    float* As      = (float*)alloc((size_t)NN * 4);
    float* Ad      = (float*)alloc((size_t)NN * 4);
    int*   rowptr  = (int*)alloc((size_t)(NN + 1) * 4);
    int*   cursor  = (int*)alloc((size_t)NN * 4);
    int*   deg     = (int*)alloc((size_t)NN * 4);
    int*   col     = (int*)alloc((size_t)ET * 4);
    int*   partials= (int*)alloc(1024 * 4);
    float* g       = (float*)alloc(512);

    // CSR build
    hipMemsetAsync(deg, 0, NN * 4, stream);
    count_kernel<<<(NE + 255) / 256, 256, 0, stream>>>(ei, deg);
    const int SB = (NN + 1023) / 1024;  // 98
    scan1_kernel<<<SB, 1024, 0, stream>>>(deg, rowptr, partials);
    scan2_kernel<<<1, 128, 0, stream>>>(partials, SB);
    scan3_kernel<<<SB, 1024, 0, stream>>>(rowptr, cursor, partials);
    scatter_kernel<<<(ET + 255) / 256, 256, 0, stream>>>(ei, cursor, col);

    const int GB = (NN + 63) / 64;  // 1563
    const int AB = (NN + 3) / 4;    // 25000

    // layer 0
    gemm_kernel<64><<<GB, 256, 0, stream>>>(x, W0, as0, ad0, hbf, As, Ad);
    aggregate_kernel<<<AB, 256, 0, stream>>>(hbf, As, Ad, rowptr, col, b0, hF, 1);
    // layer 1
    gemm_kernel<128><<<GB, 256, 0, stream>>>(hF, W1, as1, ad1, hbf, As, Ad);
    aggregate_kernel<<<AB, 256, 0, stream>>>(hbf, As, Ad, rowptr, col, b1, hF, 1);
    // layer 2
    gemm_kernel<128><<<GB, 256, 0, stream>>>(hF, W2, as2, ad2, hbf, As, Ad);
    aggregate_kernel<<<AB, 256, 0, stream>>>(hbf, As, Ad, rowptr, col, b2, hF, 0);

    // readout
    hipMemsetAsync(g, 0, 128 * 4, stream);
    sum_kernel<<<256, 256, 0, stream>>>(hF, g);
    finalize_kernel<<<1, 128, 0, stream>>>(g, Wp, bp, out);
}

// Round 3
// 575.836 us; speedup vs baseline: 1.6390x; 1.2874x over previous
//
#include <hip/hip_runtime.h>

// GAT 3-layer, N=100000 nodes, E=1.6M edges (+N self loops), Fin=64, H=128.
// CSR build: padded-counter rank pass + atomic-free scatter.
// Per layer: bf16 MFMA GEMM (fused alpha epilogue) -> per-node wave online-softmax aggregate (bf16 in/out).

#define NN 100000
#define NE 1600000
#define ET (NE + NN)   // edges + self loops
#define HD 128

typedef unsigned int uint;
typedef unsigned short ushort;
typedef __attribute__((ext_vector_type(8))) short bf16x8;
typedef __attribute__((ext_vector_type(4))) float f32x4;

__device__ __forceinline__ ushort f2b(float f) {   // fp32 -> bf16 RTN-even
    uint u = __float_as_uint(f);
    return (ushort)((u + 0x7fffu + ((u >> 16) & 1u)) >> 16);
}
__device__ __forceinline__ float b2f_lo(uint v) { return __uint_as_float(v << 16); }
__device__ __forceinline__ float b2f_hi(uint v) { return __uint_as_float(v & 0xffff0000u); }

// ---------------- converts ----------------

__global__ __launch_bounds__(256) void convx_kernel(const float* __restrict__ X,
                                                    ushort* __restrict__ Xb, int total4) {
    int i = blockIdx.x * 256 + threadIdx.x;
    if (i >= total4) return;
    float4 v = *(const float4*)&X[(size_t)i * 4];
    ushort4 o = {f2b(v.x), f2b(v.y), f2b(v.z), f2b(v.w)};
    *(ushort4*)&Xb[(size_t)i * 4] = o;
}

template <int K>
__global__ __launch_bounds__(256) void convw_kernel(const float* __restrict__ W,
                                                    ushort* __restrict__ Wt) {
    int i = blockIdx.x * 256 + threadIdx.x;
    if (i >= K * 128) return;
    int n = i / K, k = i - n * K;
    Wt[n * K + k] = f2b(W[k * 128 + n]);   // transpose: Wt[n][k] = W[k][n]
}

// ---------------- CSR build ----------------
// count+rank: padded counters (1 per 64B line) kill line-level atomic serialization.

__global__ __launch_bounds__(256) void count_rank_kernel(const int* __restrict__ ei,
                                                         int* __restrict__ degP,
                                                         int* __restrict__ rank) {
    int e = blockIdx.x * 256 + threadIdx.x;
    if (e < NE) rank[e] = atomicAdd(&degP[ei[NE + e] << 4], 1);
}

__global__ __launch_bounds__(1024) void scan1_kernel(const int* __restrict__ degP,
                                                     int* __restrict__ rowptr,
                                                     int* __restrict__ partials) {
    __shared__ int s[1024];
    int t = threadIdx.x;
    int i = blockIdx.x * 1024 + t;
    int v = (i < NN) ? (degP[i << 4] + 1) : 0;   // +1 = self loop
    s[t] = v;
    __syncthreads();
    #pragma unroll
    for (int off = 1; off < 1024; off <<= 1) {
        int add = (t >= off) ? s[t - off] : 0;
        __syncthreads();
        s[t] += add;
        __syncthreads();
    }
    if (i < NN) rowptr[i + 1] = s[t];
    if (t == 1023) partials[blockIdx.x] = s[t];
}

__global__ void scan2_kernel(int* __restrict__ partials, int nb) {
    __shared__ int s[128];
    int t = threadIdx.x;
    int v = (t < nb) ? partials[t] : 0;
    s[t] = v;
    __syncthreads();
    #pragma unroll
    for (int off = 1; off < 128; off <<= 1) {
        int add = (t >= off) ? s[t - off] : 0;
        __syncthreads();
        s[t] += add;
        __syncthreads();
    }
    if (t < nb) partials[t] = s[t] - v;  // exclusive offsets
}

__global__ __launch_bounds__(1024) void scan3_kernel(int* __restrict__ rowptr,
                                                     const int* __restrict__ partials) {
    int t = threadIdx.x;
    int i = blockIdx.x * 1024 + t;
    if (i < NN) {
        rowptr[i + 1] += partials[blockIdx.x];
        if (i == 0) rowptr[0] = 0;
    }
}

// atomic-free scatter: real edge -> rowptr[d]+rank, self loop -> last slot.
__global__ __launch_bounds__(256) void scatter_kernel(const int* __restrict__ ei,
                                                      const int* __restrict__ rowptr,
                                                      const int* __restrict__ rank,
                                                      int* __restrict__ col) {
    int e = blockIdx.x * 256 + threadIdx.x;
    if (e >= ET) return;
    if (e < NE) {
        int d = ei[NE + e];
        col[rowptr[d] + rank[e]] = ei[e];
    } else {
        int v = e - NE;
        col[rowptr[v + 1] - 1] = v;
    }
}

// ---------------- MFMA GEMM: Hbf = bf16(Xb @ W), fused fp32 alpha epilogue ----------------
// 256 thr = 4 waves; block = 128 rows x 128 cols; wave = 32 rows.
// mfma_f32_16x16x32_bf16: A lane: row=l&15, k=(l>>4)*8+[0..7]; B lane: col=l&15, same k;
// C/D lane: col=l&15, row=(l>>4)*4+j   [verified m89/m91].

template <int K>
__global__ __launch_bounds__(256) void gemm_mfma_kernel(const ushort* __restrict__ Xb,
                                                        const ushort* __restrict__ Wt,
                                                        const float* __restrict__ a_src,
                                                        const float* __restrict__ a_dst,
                                                        ushort* __restrict__ Hbf,
                                                        float* __restrict__ As,
                                                        float* __restrict__ Ad) {
    const int t = threadIdx.x;
    const int w = t >> 6;
    const int l = t & 63;
    const int c16 = l & 15;
    const int kg = l >> 4;
    const int rowBase = blockIdx.x * 128 + w * 32;

    f32x4 acc[2][8] = {};

    const int r0c = min(rowBase + c16, NN - 1);
    const int r1c = min(rowBase + 16 + c16, NN - 1);

    #pragma unroll
    for (int ks = 0; ks < K / 32; ++ks) {
        const int k0 = ks * 32 + kg * 8;
        bf16x8 a0 = *(const bf16x8*)(Xb + (size_t)r0c * K + k0);
        bf16x8 a1 = *(const bf16x8*)(Xb + (size_t)r1c * K + k0);
        #pragma unroll
        for (int n = 0; n < 8; ++n) {
            bf16x8 b = *(const bf16x8*)(Wt + (size_t)(n * 16 + c16) * K + k0);
            acc[0][n] = __builtin_amdgcn_mfma_f32_16x16x32_bf16(a0, b, acc[0][n], 0, 0, 0);
            acc[1][n] = __builtin_amdgcn_mfma_f32_16x16x32_bf16(a1, b, acc[1][n], 0, 0, 0);
        }
    }

    float avs[8], avd[8];
    #pragma unroll
    for (int n = 0; n < 8; ++n) {
        avs[n] = a_src[n * 16 + c16];
        avd[n] = a_dst[n * 16 + c16];
    }

    #pragma unroll
    for (int m = 0; m < 2; ++m) {
        #pragma unroll
        for (int j = 0; j < 4; ++j) {
            const int gr = rowBase + m * 16 + kg * 4 + j;
            const bool ok = (gr < NN);
            if (ok) {
                #pragma unroll
                for (int n = 0; n < 8; ++n)
                    Hbf[(size_t)gr * HD + n * 16 + c16] = f2b(acc[m][n][j]);
            }
            float ps = 0.f, pd = 0.f;
            #pragma unroll
            for (int n = 0; n < 8; ++n) {
                ps = fmaf(acc[m][n][j], avs[n], ps);
                pd = fmaf(acc[m][n][j], avd[n], pd);
            }
            #pragma unroll
            for (int off = 8; off >= 1; off >>= 1) {
                ps += __shfl_xor(ps, off);
                pd += __shfl_xor(pd, off);
            }
            if (ok && c16 == 0) { As[gr] = ps; Ad[gr] = pd; }
        }
    }
}

// ---------------- per-dst online softmax + aggregate: 1 wave per node ----------------

__global__ __launch_bounds__(256) void aggregate_kernel(const ushort* __restrict__ h,
                                                        const float* __restrict__ As,
                                                        const float* __restrict__ Ad,
                                                        const int* __restrict__ rowptr,
                                                        const int* __restrict__ col,
                                                        const float* __restrict__ bias,
                                                        ushort* __restrict__ out,
                                                        int relu) {
    const int lane = threadIdx.x & 63;
    const int node = blockIdx.x * 4 + (threadIdx.x >> 6);
    if (node >= NN) return;
    const int start = rowptr[node];
    const int end   = rowptr[node + 1];
    const float ad_i = Ad[node];

    float m = -1e30f;
    float denom_l = 0.f;
    float ax = 0.f, ay = 0.f;

    for (int base = start; base < end; base += 64) {
        const int cnt = min(64, end - base);
        int   sc = 0;
        float e  = -1e30f;
        if (lane < cnt) {
            sc = col[base + lane];
            float a = As[sc] + ad_i;
            e = (a > 0.f) ? a : 0.2f * a;       // leaky_relu 0.2
        }
        float cmax = e;
        #pragma unroll
        for (int off = 32; off >= 1; off >>= 1) cmax = fmaxf(cmax, __shfl_xor(cmax, off));
        if (cmax > m) {
            float s = __expf(m - cmax);
            ax *= s; ay *= s; denom_l *= s;
            m = cmax;
        }
        float w = (lane < cnt) ? __expf(e - m) : 0.f;
        denom_l += w;

        #pragma unroll 4
        for (int jj = 0; jj < cnt; ++jj) {
            int   s_j = __shfl(sc, jj);
            float w_j = __shfl(w, jj);
            uint v = *(const uint*)(h + (size_t)s_j * HD + lane * 2);
            ax = fmaf(w_j, b2f_lo(v), ax);
            ay = fmaf(w_j, b2f_hi(v), ay);
        }
    }

    #pragma unroll
    for (int off = 32; off >= 1; off >>= 1) denom_l += __shfl_xor(denom_l, off);
    float inv = 1.0f / denom_l;
    float2 bv = *(const float2*)&bias[lane * 2];
    float ox = ax * inv + bv.x;
    float oy = ay * inv + bv.y;
    if (relu) { ox = fmaxf(ox, 0.f); oy = fmaxf(oy, 0.f); }
    uint o = (uint)f2b(ox) | ((uint)f2b(oy) << 16);
    *(uint*)&out[(size_t)node * HD + lane * 2] = o;
}

// ---------------- readout ----------------

__global__ __launch_bounds__(256) void sum_kernel(const ushort* __restrict__ h,
                                                  float* __restrict__ g) {
    int t = threadIdx.x;
    int wave = t >> 6, lane = t & 63;
    float sx = 0.f, sy = 0.f;
    for (int r = blockIdx.x * 4 + wave; r < NN; r += gridDim.x * 4) {
        uint v = *(const uint*)&h[(size_t)r * HD + lane * 2];
        sx += b2f_lo(v); sy += b2f_hi(v);
    }
    __shared__ float sm[512];
    sm[wave * 128 + lane * 2]     = sx;
    sm[wave * 128 + lane * 2 + 1] = sy;
    __syncthreads();
    if (t < 128) {
        float s = sm[t] + sm[128 + t] + sm[256 + t] + sm[384 + t];
        atomicAdd(&g[t], s);
    }
}

__global__ void finalize_kernel(const float* __restrict__ g, const float* __restrict__ Wp,
                                const float* __restrict__ bp, float* __restrict__ out) {
    int t = threadIdx.x;
    float v = g[t] * Wp[t];
    #pragma unroll
    for (int m = 32; m >= 1; m >>= 1) v += __shfl_xor(v, m);
    __shared__ float red[2];
    if ((t & 63) == 0) red[t >> 6] = v;
    __syncthreads();
    if (t == 0) out[0] = (red[0] + red[1]) * (1.0f / NN) + bp[0];
}

// ---------------- launch ----------------

extern "C" void kernel_launch(void* const* d_in, const int* in_sizes, int n_in,
                              void* d_out, int out_size, void* d_ws, size_t ws_size,
                              hipStream_t stream) {
    const float* x   = (const float*)d_in[0];
    const int*   ei  = (const int*)d_in[1];
    const float* W0  = (const float*)d_in[2];
    const float* W1  = (const float*)d_in[3];
    const float* W2  = (const float*)d_in[4];
    const float* as0 = (const float*)d_in[5];
    const float* as1 = (const float*)d_in[6];
    const float* as2 = (const float*)d_in[7];
    const float* ad0 = (const float*)d_in[8];
    const float* ad1 = (const float*)d_in[9];
    const float* ad2 = (const float*)d_in[10];
    const float* b0  = (const float*)d_in[11];
    const float* b1  = (const float*)d_in[12];
    const float* b2  = (const float*)d_in[13];
    const float* Wp  = (const float*)d_in[14];
    const float* bp  = (const float*)d_in[15];
    float* out = (float*)d_out;

    char* p = (char*)d_ws;
    auto alloc = [&](size_t bytes) {
        char* r = p;
        p += (bytes + 255) & ~(size_t)255;
        return r;
    };
    ushort* xbf    = (ushort*)alloc((size_t)NN * 64 * 2);   // bf16 input
    ushort* hbf    = (ushort*)alloc((size_t)NN * HD * 2);   // gemm output (gather rows)
    ushort* abf    = (ushort*)alloc((size_t)NN * HD * 2);   // aggregate output
    ushort* Wt0    = (ushort*)alloc((size_t)64 * 128 * 2);
    ushort* Wt1    = (ushort*)alloc((size_t)128 * 128 * 2);
    ushort* Wt2    = (ushort*)alloc((size_t)128 * 128 * 2);
    float* As      = (float*)alloc((size_t)NN * 4);
    float* Ad      = (float*)alloc((size_t)NN * 4);
    int*   rowptr  = (int*)alloc((size_t)(NN + 1) * 4);
    int*   degP    = (int*)alloc((size_t)NN * 16 * 4);      // padded counters
    int*   rank    = (int*)alloc((size_t)NE * 4);
    int*   col     = (int*)alloc((size_t)ET * 4);
    int*   partials= (int*)alloc(1024 * 4);
    float* g       = (float*)alloc(512);

    // converts (independent of CSR)
    convx_kernel<<<(NN * 16 + 255) / 256, 256, 0, stream>>>(x, xbf, NN * 16);
    convw_kernel<64><<<(64 * 128 + 255) / 256, 256, 0, stream>>>(W0, Wt0);
    convw_kernel<128><<<(128 * 128 + 255) / 256, 256, 0, stream>>>(W1, Wt1);
    convw_kernel<128><<<(128 * 128 + 255) / 256, 256, 0, stream>>>(W2, Wt2);

    // CSR build
    hipMemsetAsync(degP, 0, (size_t)NN * 16 * 4, stream);
    count_rank_kernel<<<(NE + 255) / 256, 256, 0, stream>>>(ei, degP, rank);
    const int SB = (NN + 1023) / 1024;  // 98
    scan1_kernel<<<SB, 1024, 0, stream>>>(degP, rowptr, partials);
    scan2_kernel<<<1, 128, 0, stream>>>(partials, SB);
    scan3_kernel<<<SB, 1024, 0, stream>>>(rowptr, partials);
    scatter_kernel<<<(ET + 255) / 256, 256, 0, stream>>>(ei, rowptr, rank, col);

    const int GB = (NN + 127) / 128;  // 782
    const int AB = (NN + 3) / 4;      // 25000

    // layer 0
    gemm_mfma_kernel<64><<<GB, 256, 0, stream>>>(xbf, Wt0, as0, ad0, hbf, As, Ad);
    aggregate_kernel<<<AB, 256, 0, stream>>>(hbf, As, Ad, rowptr, col, b0, abf, 1);
    // layer 1
    gemm_mfma_kernel<128><<<GB, 256, 0, stream>>>(abf, Wt1, as1, ad1, hbf, As, Ad);
    aggregate_kernel<<<AB, 256, 0, stream>>>(hbf, As, Ad, rowptr, col, b1, abf, 1);
    // layer 2
    gemm_mfma_kernel<128><<<GB, 256, 0, stream>>>(abf, Wt2, as2, ad2, hbf, As, Ad);
    aggregate_kernel<<<AB, 256, 0, stream>>>(hbf, As, Ad, rowptr, col, b2, abf, 0);

    // readout
    hipMemsetAsync(g, 0, 128 * 4, stream);
    sum_kernel<<<256, 256, 0, stream>>>(abf, g);
    finalize_kernel<<<1, 128, 0, stream>>>(g, Wp, bp, out);
}

// Round 4
// 426.720 us; speedup vs baseline: 2.2117x; 1.3494x over previous
//
#include <hip/hip_runtime.h>

// GAT 3-layer, N=100000 nodes, E=1.6M edges (+N self loops), Fin=64, H=128.
// CSR build: padded-counter rank pass + atomic-free scatter.
// Per layer: bf16 MFMA GEMM (fp8-e4m3 h for the gather, fp32 alpha epilogue)
//   -> per-node wave online-softmax aggregate (4-edge groups, fp8 gather, bf16 out).

#define NN 100000
#define NE 1600000
#define ET (NE + NN)   // edges + self loops
#define HD 128

typedef unsigned int uint;
typedef unsigned short ushort;
typedef unsigned char uchar;
typedef __attribute__((ext_vector_type(8))) short bf16x8;
typedef __attribute__((ext_vector_type(8))) ushort u16x8;
typedef __attribute__((ext_vector_type(4))) float f32x4;
typedef __attribute__((ext_vector_type(2))) float f32x2;

__device__ __forceinline__ ushort f2b(float f) {   // fp32 -> bf16 RTN-even
    uint u = __float_as_uint(f);
    return (ushort)((u + 0x7fffu + ((u >> 16) & 1u)) >> 16);
}
__device__ __forceinline__ float b2f_lo(uint v) { return __uint_as_float(v << 16); }
__device__ __forceinline__ float b2f_hi(uint v) { return __uint_as_float(v & 0xffff0000u); }
__device__ __forceinline__ uchar f2fp8(float f) {  // fp32 -> fp8 e4m3 (OCP), RNE+sat
    return (uchar)(__builtin_amdgcn_cvt_pk_fp8_f32(f, f, 0, false) & 0xff);
}

// ---------------- converts ----------------

__global__ __launch_bounds__(256) void convx_kernel(const float* __restrict__ X,
                                                    ushort* __restrict__ Xb, int total4) {
    int i = blockIdx.x * 256 + threadIdx.x;
    if (i >= total4) return;
    float4 v = *(const float4*)&X[(size_t)i * 4];
    ushort4 o = {f2b(v.x), f2b(v.y), f2b(v.z), f2b(v.w)};
    *(ushort4*)&Xb[(size_t)i * 4] = o;
}

template <int K>
__global__ __launch_bounds__(256) void convw_kernel(const float* __restrict__ W,
                                                    ushort* __restrict__ Wt) {
    int i = blockIdx.x * 256 + threadIdx.x;
    if (i >= K * 128) return;
    int n = i / K, k = i - n * K;
    Wt[n * K + k] = f2b(W[k * 128 + n]);   // transpose: Wt[n][k] = W[k][n]
}

// ---------------- CSR build ----------------

__global__ __launch_bounds__(256) void count_rank_kernel(const int* __restrict__ ei,
                                                         int* __restrict__ degP,
                                                         int* __restrict__ rank) {
    int e = blockIdx.x * 256 + threadIdx.x;
    if (e < NE) rank[e] = atomicAdd(&degP[ei[NE + e] << 4], 1);
}

__global__ __launch_bounds__(1024) void scan1_kernel(const int* __restrict__ degP,
                                                     int* __restrict__ rowptr,
                                                     int* __restrict__ partials) {
    __shared__ int s[1024];
    int t = threadIdx.x;
    int i = blockIdx.x * 1024 + t;
    int v = (i < NN) ? (degP[i << 4] + 1) : 0;   // +1 = self loop
    s[t] = v;
    __syncthreads();
    #pragma unroll
    for (int off = 1; off < 1024; off <<= 1) {
        int add = (t >= off) ? s[t - off] : 0;
        __syncthreads();
        s[t] += add;
        __syncthreads();
    }
    if (i < NN) rowptr[i + 1] = s[t];
    if (t == 1023) partials[blockIdx.x] = s[t];
}

__global__ void scan2_kernel(int* __restrict__ partials, int nb) {
    __shared__ int s[128];
    int t = threadIdx.x;
    int v = (t < nb) ? partials[t] : 0;
    s[t] = v;
    __syncthreads();
    #pragma unroll
    for (int off = 1; off < 128; off <<= 1) {
        int add = (t >= off) ? s[t - off] : 0;
        __syncthreads();
        s[t] += add;
        __syncthreads();
    }
    if (t < nb) partials[t] = s[t] - v;  // exclusive offsets
}

__global__ __launch_bounds__(1024) void scan3_kernel(int* __restrict__ rowptr,
                                                     const int* __restrict__ partials) {
    int t = threadIdx.x;
    int i = blockIdx.x * 1024 + t;
    if (i < NN) {
        rowptr[i + 1] += partials[blockIdx.x];
        if (i == 0) rowptr[0] = 0;
    }
}

__global__ __launch_bounds__(256) void scatter_kernel(const int* __restrict__ ei,
                                                      const int* __restrict__ rowptr,
                                                      const int* __restrict__ rank,
                                                      int* __restrict__ col) {
    int e = blockIdx.x * 256 + threadIdx.x;
    if (e >= ET) return;
    if (e < NE) {
        int d = ei[NE + e];
        col[rowptr[d] + rank[e]] = ei[e];
    } else {
        int v = e - NE;
        col[rowptr[v + 1] - 1] = v;
    }
}

// ---------------- MFMA GEMM: Hf8 = fp8(Xb @ W), fused fp32 alpha epilogue ----------------
// 256 thr = 4 waves; block = 128 rows x 128 cols; wave = 32 rows.
// mfma_f32_16x16x32_bf16 C/D: col=l&15, row=(l>>4)*4+j  [verified m89/m91].

template <int K>
__global__ __launch_bounds__(256) void gemm_mfma_kernel(const ushort* __restrict__ Xb,
                                                        const ushort* __restrict__ Wt,
                                                        const float* __restrict__ a_src,
                                                        const float* __restrict__ a_dst,
                                                        uchar* __restrict__ Hf8,
                                                        float* __restrict__ As,
                                                        float* __restrict__ Ad) {
    const int t = threadIdx.x;
    const int w = t >> 6;
    const int l = t & 63;
    const int c16 = l & 15;
    const int kg = l >> 4;
    const int rowBase = blockIdx.x * 128 + w * 32;

    f32x4 acc[2][8] = {};

    const int r0c = min(rowBase + c16, NN - 1);
    const int r1c = min(rowBase + 16 + c16, NN - 1);

    #pragma unroll
    for (int ks = 0; ks < K / 32; ++ks) {
        const int k0 = ks * 32 + kg * 8;
        bf16x8 a0 = *(const bf16x8*)(Xb + (size_t)r0c * K + k0);
        bf16x8 a1 = *(const bf16x8*)(Xb + (size_t)r1c * K + k0);
        #pragma unroll
        for (int n = 0; n < 8; ++n) {
            bf16x8 b = *(const bf16x8*)(Wt + (size_t)(n * 16 + c16) * K + k0);
            acc[0][n] = __builtin_amdgcn_mfma_f32_16x16x32_bf16(a0, b, acc[0][n], 0, 0, 0);
            acc[1][n] = __builtin_amdgcn_mfma_f32_16x16x32_bf16(a1, b, acc[1][n], 0, 0, 0);
        }
    }

    float avs[8], avd[8];
    #pragma unroll
    for (int n = 0; n < 8; ++n) {
        avs[n] = a_src[n * 16 + c16];
        avd[n] = a_dst[n * 16 + c16];
    }

    #pragma unroll
    for (int m = 0; m < 2; ++m) {
        #pragma unroll
        for (int j = 0; j < 4; ++j) {
            const int gr = rowBase + m * 16 + kg * 4 + j;
            const bool ok = (gr < NN);
            if (ok) {
                #pragma unroll
                for (int n = 0; n < 8; ++n)
                    Hf8[(size_t)gr * HD + n * 16 + c16] = f2fp8(acc[m][n][j]);
            }
            float ps = 0.f, pd = 0.f;
            #pragma unroll
            for (int n = 0; n < 8; ++n) {
                ps = fmaf(acc[m][n][j], avs[n], ps);
                pd = fmaf(acc[m][n][j], avd[n], pd);
            }
            #pragma unroll
            for (int off = 8; off >= 1; off >>= 1) {
                ps += __shfl_xor(ps, off);
                pd += __shfl_xor(pd, off);
            }
            if (ok && c16 == 0) { As[gr] = ps; Ad[gr] = pd; }
        }
    }
}

// ---------------- per-dst online softmax + aggregate ----------------
// 1 wave per node; wave = 4 groups x 16 lanes. Per inner iter each group gathers a
// DIFFERENT edge's fp8 row (16 lanes x 8B = 128B coalesced) -> 4 rows per load instr.

__global__ __launch_bounds__(256) void aggregate_kernel(const uchar* __restrict__ h8,
                                                        const float* __restrict__ As,
                                                        const float* __restrict__ Ad,
                                                        const int* __restrict__ rowptr,
                                                        const int* __restrict__ col,
                                                        const float* __restrict__ bias,
                                                        ushort* __restrict__ out,
                                                        int relu) {
    const int lane = threadIdx.x & 63;
    const int g = lane >> 4;        // edge-group 0..3
    const int q = lane & 15;        // lane within group -> feats [q*8, q*8+8)
    const int node = blockIdx.x * 4 + (threadIdx.x >> 6);
    if (node >= NN) return;
    const int start = rowptr[node];
    const int end   = rowptr[node + 1];
    const float ad_i = Ad[node];

    float m = -1e30f;
    float denom = 0.f;
    float acc[8] = {};

    for (int base = start; base < end; base += 64) {
        const int cnt = min(64, end - base);
        int   sc = 0;
        float e  = -1e30f;
        if (lane < cnt) {
            sc = col[base + lane];
            float a = As[sc] + ad_i;
            e = (a > 0.f) ? a : 0.2f * a;       // leaky_relu 0.2
        }
        float cmax = e;
        #pragma unroll
        for (int off = 32; off >= 1; off >>= 1) cmax = fmaxf(cmax, __shfl_xor(cmax, off));
        if (cmax > m) {                          // uniform online rescale
            float s = __expf(m - cmax);
            #pragma unroll
            for (int i = 0; i < 8; ++i) acc[i] *= s;
            denom *= s;
            m = cmax;
        }
        float w = (lane < cnt) ? __expf(e - m) : 0.f;
        denom += w;

        #pragma unroll 2
        for (int jj = 0; jj < cnt; jj += 4) {
            int   idx = jj + g;                  // <= 63 always
            float w_j = __shfl(w, idx);
            int   s_j = __shfl(sc, idx);
            if (w_j > 0.f) {                     // group-uniform; skips tail groups
                uint2 v = *(const uint2*)(h8 + (size_t)s_j * HD + q * 8);
                f32x2 p0 = __builtin_amdgcn_cvt_pk_f32_fp8(v.x, false);
                f32x2 p1 = __builtin_amdgcn_cvt_pk_f32_fp8(v.x, true);
                f32x2 p2 = __builtin_amdgcn_cvt_pk_f32_fp8(v.y, false);
                f32x2 p3 = __builtin_amdgcn_cvt_pk_f32_fp8(v.y, true);
                acc[0] = fmaf(w_j, p0.x, acc[0]);
                acc[1] = fmaf(w_j, p0.y, acc[1]);
                acc[2] = fmaf(w_j, p1.x, acc[2]);
                acc[3] = fmaf(w_j, p1.y, acc[3]);
                acc[4] = fmaf(w_j, p2.x, acc[4]);
                acc[5] = fmaf(w_j, p2.y, acc[5]);
                acc[6] = fmaf(w_j, p3.x, acc[6]);
                acc[7] = fmaf(w_j, p3.y, acc[7]);
            }
        }
    }

    // cross-group feature reduce (groups hold partial sums of the same feats)
    #pragma unroll
    for (int i = 0; i < 8; ++i) {
        acc[i] += __shfl_xor(acc[i], 16);
        acc[i] += __shfl_xor(acc[i], 32);
    }
    #pragma unroll
    for (int off = 32; off >= 1; off >>= 1) denom += __shfl_xor(denom, off);

    if (g == 0) {
        float inv = 1.0f / denom;
        u16x8 o;
        #pragma unroll
        for (int i = 0; i < 8; ++i) {
            float v = fmaf(acc[i], inv, bias[q * 8 + i]);
            if (relu) v = fmaxf(v, 0.f);
            o[i] = f2b(v);
        }
        *(u16x8*)&out[(size_t)node * HD + q * 8] = o;
    }
}

// ---------------- readout ----------------

__global__ __launch_bounds__(256) void sum_kernel(const ushort* __restrict__ h,
                                                  float* __restrict__ g) {
    int t = threadIdx.x;
    int wave = t >> 6, lane = t & 63;
    float sx = 0.f, sy = 0.f;
    for (int r = blockIdx.x * 4 + wave; r < NN; r += gridDim.x * 4) {
        uint v = *(const uint*)&h[(size_t)r * HD + lane * 2];
        sx += b2f_lo(v); sy += b2f_hi(v);
    }
    __shared__ float sm[512];
    sm[wave * 128 + lane * 2]     = sx;
    sm[wave * 128 + lane * 2 + 1] = sy;
    __syncthreads();
    if (t < 128) {
        float s = sm[t] + sm[128 + t] + sm[256 + t] + sm[384 + t];
        atomicAdd(&g[t], s);
    }
}

__global__ void finalize_kernel(const float* __restrict__ g, const float* __restrict__ Wp,
                                const float* __restrict__ bp, float* __restrict__ out) {
    int t = threadIdx.x;
    float v = g[t] * Wp[t];
    #pragma unroll
    for (int m = 32; m >= 1; m >>= 1) v += __shfl_xor(v, m);
    __shared__ float red[2];
    if ((t & 63) == 0) red[t >> 6] = v;
    __syncthreads();
    if (t == 0) out[0] = (red[0] + red[1]) * (1.0f / NN) + bp[0];
}

// ---------------- launch ----------------

extern "C" void kernel_launch(void* const* d_in, const int* in_sizes, int n_in,
                              void* d_out, int out_size, void* d_ws, size_t ws_size,
                              hipStream_t stream) {
    const float* x   = (const float*)d_in[0];
    const int*   ei  = (const int*)d_in[1];
    const float* W0  = (const float*)d_in[2];
    const float* W1  = (const float*)d_in[3];
    const float* W2  = (const float*)d_in[4];
    const float* as0 = (const float*)d_in[5];
    const float* as1 = (const float*)d_in[6];
    const float* as2 = (const float*)d_in[7];
    const float* ad0 = (const float*)d_in[8];
    const float* ad1 = (const float*)d_in[9];
    const float* ad2 = (const float*)d_in[10];
    const float* b0  = (const float*)d_in[11];
    const float* b1  = (const float*)d_in[12];
    const float* b2  = (const float*)d_in[13];
    const float* Wp  = (const float*)d_in[14];
    const float* bp  = (const float*)d_in[15];
    float* out = (float*)d_out;

    char* p = (char*)d_ws;
    auto alloc = [&](size_t bytes) {
        char* r = p;
        p += (bytes + 255) & ~(size_t)255;
        return r;
    };
    ushort* xbf    = (ushort*)alloc((size_t)NN * 64 * 2);   // bf16 input
    uchar*  hf8    = (uchar*)alloc((size_t)NN * HD);        // fp8 gather rows
    ushort* abf    = (ushort*)alloc((size_t)NN * HD * 2);   // aggregate output (bf16)
    ushort* Wt0    = (ushort*)alloc((size_t)64 * 128 * 2);
    ushort* Wt1    = (ushort*)alloc((size_t)128 * 128 * 2);
    ushort* Wt2    = (ushort*)alloc((size_t)128 * 128 * 2);
    float* As      = (float*)alloc((size_t)NN * 4);
    float* Ad      = (float*)alloc((size_t)NN * 4);
    int*   rowptr  = (int*)alloc((size_t)(NN + 1) * 4);
    int*   degP    = (int*)alloc((size_t)NN * 16 * 4);      // padded counters
    int*   rank    = (int*)alloc((size_t)NE * 4);
    int*   col     = (int*)alloc((size_t)ET * 4);
    int*   partials= (int*)alloc(1024 * 4);
    float* g       = (float*)alloc(512);

    // converts (independent of CSR)
    convx_kernel<<<(NN * 16 + 255) / 256, 256, 0, stream>>>(x, xbf, NN * 16);
    convw_kernel<64><<<(64 * 128 + 255) / 256, 256, 0, stream>>>(W0, Wt0);
    convw_kernel<128><<<(128 * 128 + 255) / 256, 256, 0, stream>>>(W1, Wt1);
    convw_kernel<128><<<(128 * 128 + 255) / 256, 256, 0, stream>>>(W2, Wt2);

    // CSR build
    hipMemsetAsync(degP, 0, (size_t)NN * 16 * 4, stream);
    count_rank_kernel<<<(NE + 255) / 256, 256, 0, stream>>>(ei, degP, rank);
    const int SB = (NN + 1023) / 1024;  // 98
    scan1_kernel<<<SB, 1024, 0, stream>>>(degP, rowptr, partials);
    scan2_kernel<<<1, 128, 0, stream>>>(partials, SB);
    scan3_kernel<<<SB, 1024, 0, stream>>>(rowptr, partials);
    scatter_kernel<<<(ET + 255) / 256, 256, 0, stream>>>(ei, rowptr, rank, col);

    const int GB = (NN + 127) / 128;  // 782
    const int AB = (NN + 3) / 4;      // 25000

    // layer 0
    gemm_mfma_kernel<64><<<GB, 256, 0, stream>>>(xbf, Wt0, as0, ad0, hf8, As, Ad);
    aggregate_kernel<<<AB, 256, 0, stream>>>(hf8, As, Ad, rowptr, col, b0, abf, 1);
    // layer 1
    gemm_mfma_kernel<128><<<GB, 256, 0, stream>>>(abf, Wt1, as1, ad1, hf8, As, Ad);
    aggregate_kernel<<<AB, 256, 0, stream>>>(hf8, As, Ad, rowptr, col, b1, abf, 1);
    // layer 2
    gemm_mfma_kernel<128><<<GB, 256, 0, stream>>>(abf, Wt2, as2, ad2, hf8, As, Ad);
    aggregate_kernel<<<AB, 256, 0, stream>>>(hf8, As, Ad, rowptr, col, b2, abf, 0);

    // readout
    hipMemsetAsync(g, 0, 128 * 4, stream);
    sum_kernel<<<256, 256, 0, stream>>>(abf, g);
    finalize_kernel<<<1, 128, 0, stream>>>(g, Wp, bp, out);
}

// Round 5
// 372.196 us; speedup vs baseline: 2.5357x; 1.1465x over previous
//
#include <hip/hip_runtime.h>

// GAT 3-layer, N=100000 nodes, E=1.6M edges (+N self loops), Fin=64, H=128.
// CSR build: bucketed two-phase counting sort (LDS histograms, block-reserved ranges).
// Per layer: bf16 MFMA GEMM (fp8-e4m3 h for the gather, fp32 alpha epilogue)
//   -> per-node (2 nodes/wave) online-softmax aggregate (fp8 gather, bf16 out).

#define NN 100000
#define NE 1600000
#define ET (NE + NN)   // edges + self loops
#define HD 128
#define NB 782         // buckets = ceil(NN / 128)
#define EB 782         // edge-partition blocks = ceil(NE / 2048)

typedef unsigned int uint;
typedef unsigned short ushort;
typedef unsigned char uchar;
typedef __attribute__((ext_vector_type(8))) short bf16x8;
typedef __attribute__((ext_vector_type(8))) ushort u16x8;
typedef __attribute__((ext_vector_type(4))) float f32x4;
typedef __attribute__((ext_vector_type(2))) float f32x2;

__device__ __forceinline__ ushort f2b(float f) {   // fp32 -> bf16 RTN-even
    uint u = __float_as_uint(f);
    return (ushort)((u + 0x7fffu + ((u >> 16) & 1u)) >> 16);
}
__device__ __forceinline__ float b2f_lo(uint v) { return __uint_as_float(v << 16); }
__device__ __forceinline__ float b2f_hi(uint v) { return __uint_as_float(v & 0xffff0000u); }
__device__ __forceinline__ uchar f2fp8(float f) {  // fp32 -> fp8 e4m3 (OCP), RNE+sat
    return (uchar)(__builtin_amdgcn_cvt_pk_fp8_f32(f, f, 0, false) & 0xff);
}

// ---------------- converts ----------------

__global__ __launch_bounds__(256) void convx_kernel(const float* __restrict__ X,
                                                    ushort* __restrict__ Xb, int total4) {
    int i = blockIdx.x * 256 + threadIdx.x;
    if (i >= total4) return;
    float4 v = *(const float4*)&X[(size_t)i * 4];
    ushort4 o = {f2b(v.x), f2b(v.y), f2b(v.z), f2b(v.w)};
    *(ushort4*)&Xb[(size_t)i * 4] = o;
}

template <int K>
__global__ __launch_bounds__(256) void convw_kernel(const float* __restrict__ W,
                                                    ushort* __restrict__ Wt) {
    int i = blockIdx.x * 256 + threadIdx.x;
    if (i >= K * 128) return;
    int n = i / K, k = i - n * K;
    Wt[n * K + k] = f2b(W[k * 128 + n]);   // transpose: Wt[n][k] = W[k][n]
}

// ---------------- CSR build: bucketed two-phase counting sort ----------------
// bucket b = dst >> 7 (128 nodes per bucket).

// P1a: global bucket histogram (LDS hist, batched global atomics on padded counters)
__global__ __launch_bounds__(256) void p1a_hist_kernel(const int* __restrict__ eidst,
                                                       int* __restrict__ bucketCnt) {
    __shared__ int cnt[NB];
    const int t = threadIdx.x;
    for (int c = t; c < NB; c += 256) cnt[c] = 0;
    __syncthreads();
    const int base = blockIdx.x * 2048;
    #pragma unroll
    for (int i = 0; i < 8; ++i) {
        int e = base + t + i * 256;
        if (e < NE) atomicAdd(&cnt[eidst[e] >> 7], 1);
    }
    __syncthreads();
    for (int c = t; c < NB; c += 256) {
        int v = cnt[c];
        if (v) atomicAdd(&bucketCnt[c << 4], v);
    }
}

// P1b: exclusive scan of bucket counts -> off[NB+1]; init cur (padded) = off
__global__ __launch_bounds__(1024) void p1b_bscan_kernel(const int* __restrict__ bucketCnt,
                                                         int* __restrict__ off,
                                                         int* __restrict__ cur) {
    __shared__ int s[1024];
    const int t = threadIdx.x;
    int v = (t < NB) ? bucketCnt[t << 4] : 0;
    s[t] = v;
    __syncthreads();
    #pragma unroll
    for (int o = 1; o < 1024; o <<= 1) {
        int add = (t >= o) ? s[t - o] : 0;
        __syncthreads();
        s[t] += add;
        __syncthreads();
    }
    if (t < NB) {
        int ex = s[t] - v;
        off[t] = ex;
        cur[t << 4] = ex;
    }
    if (t == 1023) off[NB] = s[t];
}

// P1c: partition edges into bucket-grouped (src,dst) pairs
__global__ __launch_bounds__(256) void p1c_part_kernel(const int* __restrict__ ei,
                                                       int* __restrict__ cur,
                                                       uint2* __restrict__ stage) {
    __shared__ int cnt[NB];
    const int t = threadIdx.x;
    for (int c = t; c < NB; c += 256) cnt[c] = 0;
    __syncthreads();
    const int base = blockIdx.x * 2048;
    int src[8], dst[8];
    #pragma unroll
    for (int i = 0; i < 8; ++i) {
        int e = base + t + i * 256;
        if (e < NE) {
            src[i] = ei[e];
            dst[i] = ei[NE + e];
            atomicAdd(&cnt[dst[i] >> 7], 1);
        } else dst[i] = -1;
    }
    __syncthreads();
    for (int c = t; c < NB; c += 256) {
        int v = cnt[c];
        if (v) cnt[c] = atomicAdd(&cur[c << 4], v);   // cnt becomes this block's base
    }
    __syncthreads();
    #pragma unroll
    for (int i = 0; i < 8; ++i) {
        if (dst[i] >= 0) {
            int pos = atomicAdd(&cnt[dst[i] >> 7], 1);
            stage[pos] = (uint2){(uint)src[i], (uint)dst[i]};
        }
    }
}

// P2a: per-bucket degree count
__global__ __launch_bounds__(256) void p2a_deg_kernel(const uint2* __restrict__ stage,
                                                      const int* __restrict__ off,
                                                      int* __restrict__ deg) {
    __shared__ int d128[128];
    const int t = threadIdx.x;
    const int b = blockIdx.x;
    if (t < 128) d128[t] = 0;
    __syncthreads();
    const int s0 = off[b], s1 = off[b + 1];
    for (int i = s0 + t; i < s1; i += 256)
        atomicAdd(&d128[stage[i].y & 127], 1);
    __syncthreads();
    if (t < 128) {
        int node = (b << 7) + t;
        if (node < NN) deg[node] = d128[t];
    }
}

__global__ __launch_bounds__(1024) void scan1_kernel(const int* __restrict__ deg,
                                                     int* __restrict__ rowptr,
                                                     int* __restrict__ partials) {
    __shared__ int s[1024];
    int t = threadIdx.x;
    int i = blockIdx.x * 1024 + t;
    int v = (i < NN) ? (deg[i] + 1) : 0;   // +1 = self loop
    s[t] = v;
    __syncthreads();
    #pragma unroll
    for (int off = 1; off < 1024; off <<= 1) {
        int add = (t >= off) ? s[t - off] : 0;
        __syncthreads();
        s[t] += add;
        __syncthreads();
    }
    if (i < NN) rowptr[i + 1] = s[t];
    if (t == 1023) partials[blockIdx.x] = s[t];
}

__global__ void scan2_kernel(int* __restrict__ partials, int nb) {
    __shared__ int s[128];
    int t = threadIdx.x;
    int v = (t < nb) ? partials[t] : 0;
    s[t] = v;
    __syncthreads();
    #pragma unroll
    for (int off = 1; off < 128; off <<= 1) {
        int add = (t >= off) ? s[t - off] : 0;
        __syncthreads();
        s[t] += add;
        __syncthreads();
    }
    if (t < nb) partials[t] = s[t] - v;  // exclusive offsets
}

__global__ __launch_bounds__(1024) void scan3_kernel(int* __restrict__ rowptr,
                                                     const int* __restrict__ partials) {
    int t = threadIdx.x;
    int i = blockIdx.x * 1024 + t;
    if (i < NN) {
        rowptr[i + 1] += partials[blockIdx.x];
        if (i == 0) rowptr[0] = 0;
    }
}

// P2c: per-bucket placement (col writes land in a block-exclusive contiguous window)
__global__ __launch_bounds__(256) void p2c_place_kernel(const uint2* __restrict__ stage,
                                                        const int* __restrict__ off,
                                                        const int* __restrict__ rowptr,
                                                        int* __restrict__ col) {
    __shared__ int cur128[128];
    const int t = threadIdx.x;
    const int b = blockIdx.x;
    if (t < 128) {
        int node = (b << 7) + t;
        if (node < NN) {
            cur128[t] = rowptr[node];
            col[rowptr[node + 1] - 1] = node;   // self loop -> last slot
        } else cur128[t] = 0;
    }
    __syncthreads();
    const int s0 = off[b], s1 = off[b + 1];
    for (int i = s0 + t; i < s1; i += 256) {
        uint2 p = stage[i];
        int pos = atomicAdd(&cur128[p.y & 127], 1);
        col[pos] = (int)p.x;
    }
}

// ---------------- MFMA GEMM: Hf8 = fp8(Xb @ W), fused fp32 alpha epilogue ----------------
// 256 thr = 4 waves; block = 128 rows x 128 cols; wave = 32 rows.
// mfma_f32_16x16x32_bf16 C/D: col=l&15, row=(l>>4)*4+j  [verified m89/m91].

template <int K>
__global__ __launch_bounds__(256) void gemm_mfma_kernel(const ushort* __restrict__ Xb,
                                                        const ushort* __restrict__ Wt,
                                                        const float* __restrict__ a_src,
                                                        const float* __restrict__ a_dst,
                                                        uchar* __restrict__ Hf8,
                                                        float* __restrict__ As,
                                                        float* __restrict__ Ad) {
    const int t = threadIdx.x;
    const int w = t >> 6;
    const int l = t & 63;
    const int c16 = l & 15;
    const int kg = l >> 4;
    const int rowBase = blockIdx.x * 128 + w * 32;

    f32x4 acc[2][8] = {};

    const int r0c = min(rowBase + c16, NN - 1);
    const int r1c = min(rowBase + 16 + c16, NN - 1);

    #pragma unroll
    for (int ks = 0; ks < K / 32; ++ks) {
        const int k0 = ks * 32 + kg * 8;
        bf16x8 a0 = *(const bf16x8*)(Xb + (size_t)r0c * K + k0);
        bf16x8 a1 = *(const bf16x8*)(Xb + (size_t)r1c * K + k0);
        #pragma unroll
        for (int n = 0; n < 8; ++n) {
            bf16x8 b = *(const bf16x8*)(Wt + (size_t)(n * 16 + c16) * K + k0);
            acc[0][n] = __builtin_amdgcn_mfma_f32_16x16x32_bf16(a0, b, acc[0][n], 0, 0, 0);
            acc[1][n] = __builtin_amdgcn_mfma_f32_16x16x32_bf16(a1, b, acc[1][n], 0, 0, 0);
        }
    }

    float avs[8], avd[8];
    #pragma unroll
    for (int n = 0; n < 8; ++n) {
        avs[n] = a_src[n * 16 + c16];
        avd[n] = a_dst[n * 16 + c16];
    }

    #pragma unroll
    for (int m = 0; m < 2; ++m) {
        #pragma unroll
        for (int j = 0; j < 4; ++j) {
            const int gr = rowBase + m * 16 + kg * 4 + j;
            const bool ok = (gr < NN);
            if (ok) {
                #pragma unroll
                for (int n = 0; n < 8; ++n)
                    Hf8[(size_t)gr * HD + n * 16 + c16] = f2fp8(acc[m][n][j]);
            }
            float ps = 0.f, pd = 0.f;
            #pragma unroll
            for (int n = 0; n < 8; ++n) {
                ps = fmaf(acc[m][n][j], avs[n], ps);
                pd = fmaf(acc[m][n][j], avd[n], pd);
            }
            #pragma unroll
            for (int off = 8; off >= 1; off >>= 1) {
                ps += __shfl_xor(ps, off);
                pd += __shfl_xor(pd, off);
            }
            if (ok && c16 == 0) { As[gr] = ps; Ad[gr] = pd; }
        }
    }
}

// ---------------- per-dst online softmax + aggregate ----------------
// 2 nodes per wave (32 lanes each); per node: 2 groups x 16 lanes. Branchless inner
// loop, 2 edges/group/iter -> 4 independent fp8-row gather streams per wave.

__global__ __launch_bounds__(256) void aggregate_kernel(const uchar* __restrict__ h8,
                                                        const float* __restrict__ As,
                                                        const float* __restrict__ Ad,
                                                        const int* __restrict__ rowptr,
                                                        const int* __restrict__ col,
                                                        const float* __restrict__ bias,
                                                        ushort* __restrict__ out,
                                                        int relu) {
    const int lane  = threadIdx.x & 63;
    const int sub   = lane & 31;        // lane within node
    const int g2    = sub >> 4;         // edge-group 0/1
    const int q     = sub & 15;         // feature lane -> feats [q*8, q*8+8)
    const int lbase = lane & 32;        // node-half base for shfl
    const int node  = blockIdx.x * 8 + ((threadIdx.x >> 6) << 1) + (lane >> 5);
    // grid is exact: 12500 * 8 == NN

    const int start = rowptr[node];
    const int end   = rowptr[node + 1];
    const float ad_i = Ad[node];

    float m = -1e30f;
    float denom = 0.f;
    float acc[8] = {};

    for (int base = start; base < end; base += 32) {
        const int cnt = min(32, end - base);
        int   sc = 0;
        float e  = -1e30f;
        if (sub < cnt) {
            sc = col[base + sub];
            float a = As[sc] + ad_i;
            e = (a > 0.f) ? a : 0.2f * a;       // leaky_relu 0.2
        }
        float cmax = e;
        #pragma unroll
        for (int off = 16; off >= 1; off >>= 1) cmax = fmaxf(cmax, __shfl_xor(cmax, off));
        // branchless online rescale (s==0 on first chunk, ==1 when max unchanged)
        float s = __expf(fminf(m - cmax, 0.f));
        m = fmaxf(m, cmax);
        #pragma unroll
        for (int i = 0; i < 8; ++i) acc[i] *= s;
        denom *= s;

        float w = (sub < cnt) ? __expf(e - m) : 0.f;
        denom += w;

        for (int jj = 0; jj < cnt; jj += 4) {
            const int i0 = lbase | (jj + 2 * g2);
            float w0 = __shfl(w, i0);
            float w1 = __shfl(w, i0 + 1);
            int   s0 = __shfl(sc, i0);
            int   s1 = __shfl(sc, i0 + 1);
            uint2 v0 = *(const uint2*)(h8 + (size_t)s0 * HD + q * 8);
            uint2 v1 = *(const uint2*)(h8 + (size_t)s1 * HD + q * 8);
            f32x2 p0 = __builtin_amdgcn_cvt_pk_f32_fp8(v0.x, false);
            f32x2 p1 = __builtin_amdgcn_cvt_pk_f32_fp8(v0.x, true);
            f32x2 p2 = __builtin_amdgcn_cvt_pk_f32_fp8(v0.y, false);
            f32x2 p3 = __builtin_amdgcn_cvt_pk_f32_fp8(v0.y, true);
            acc[0] = fmaf(w0, p0.x, acc[0]); acc[1] = fmaf(w0, p0.y, acc[1]);
            acc[2] = fmaf(w0, p1.x, acc[2]); acc[3] = fmaf(w0, p1.y, acc[3]);
            acc[4] = fmaf(w0, p2.x, acc[4]); acc[5] = fmaf(w0, p2.y, acc[5]);
            acc[6] = fmaf(w0, p3.x, acc[6]); acc[7] = fmaf(w0, p3.y, acc[7]);
            f32x2 r0 = __builtin_amdgcn_cvt_pk_f32_fp8(v1.x, false);
            f32x2 r1 = __builtin_amdgcn_cvt_pk_f32_fp8(v1.x, true);
            f32x2 r2 = __builtin_amdgcn_cvt_pk_f32_fp8(v1.y, false);
            f32x2 r3 = __builtin_amdgcn_cvt_pk_f32_fp8(v1.y, true);
            acc[0] = fmaf(w1, r0.x, acc[0]); acc[1] = fmaf(w1, r0.y, acc[1]);
            acc[2] = fmaf(w1, r1.x, acc[2]); acc[3] = fmaf(w1, r1.y, acc[3]);
            acc[4] = fmaf(w1, r2.x, acc[4]); acc[5] = fmaf(w1, r2.y, acc[5]);
            acc[6] = fmaf(w1, r3.x, acc[6]); acc[7] = fmaf(w1, r3.y, acc[7]);
        }
    }

    // cross-group feature reduce (xor 16 combines the node's two groups)
    #pragma unroll
    for (int i = 0; i < 8; ++i) acc[i] += __shfl_xor(acc[i], 16);
    #pragma unroll
    for (int off = 16; off >= 1; off >>= 1) denom += __shfl_xor(denom, off);

    if (g2 == 0) {
        float inv = 1.0f / denom;
        float4 bv0 = *(const float4*)&bias[q * 8];
        float4 bv1 = *(const float4*)&bias[q * 8 + 4];
        float bb[8] = {bv0.x, bv0.y, bv0.z, bv0.w, bv1.x, bv1.y, bv1.z, bv1.w};
        u16x8 o;
        #pragma unroll
        for (int i = 0; i < 8; ++i) {
            float v = fmaf(acc[i], inv, bb[i]);
            if (relu) v = fmaxf(v, 0.f);
            o[i] = f2b(v);
        }
        *(u16x8*)&out[(size_t)node * HD + q * 8] = o;
    }
}

// ---------------- readout ----------------

__global__ __launch_bounds__(256) void sum_kernel(const ushort* __restrict__ h,
                                                  float* __restrict__ g) {
    int t = threadIdx.x;
    int wave = t >> 6, lane = t & 63;
    float sx = 0.f, sy = 0.f;
    for (int r = blockIdx.x * 4 + wave; r < NN; r += gridDim.x * 4) {
        uint v = *(const uint*)&h[(size_t)r * HD + lane * 2];
        sx += b2f_lo(v); sy += b2f_hi(v);
    }
    __shared__ float sm[512];
    sm[wave * 128 + lane * 2]     = sx;
    sm[wave * 128 + lane * 2 + 1] = sy;
    __syncthreads();
    if (t < 128) {
        float s = sm[t] + sm[128 + t] + sm[256 + t] + sm[384 + t];
        atomicAdd(&g[t], s);
    }
}

__global__ void finalize_kernel(const float* __restrict__ g, const float* __restrict__ Wp,
                                const float* __restrict__ bp, float* __restrict__ out) {
    int t = threadIdx.x;
    float v = g[t] * Wp[t];
    #pragma unroll
    for (int m = 32; m >= 1; m >>= 1) v += __shfl_xor(v, m);
    __shared__ float red[2];
    if ((t & 63) == 0) red[t >> 6] = v;
    __syncthreads();
    if (t == 0) out[0] = (red[0] + red[1]) * (1.0f / NN) + bp[0];
}

// ---------------- launch ----------------

extern "C" void kernel_launch(void* const* d_in, const int* in_sizes, int n_in,
                              void* d_out, int out_size, void* d_ws, size_t ws_size,
                              hipStream_t stream) {
    const float* x   = (const float*)d_in[0];
    const int*   ei  = (const int*)d_in[1];
    const float* W0  = (const float*)d_in[2];
    const float* W1  = (const float*)d_in[3];
    const float* W2  = (const float*)d_in[4];
    const float* as0 = (const float*)d_in[5];
    const float* as1 = (const float*)d_in[6];
    const float* as2 = (const float*)d_in[7];
    const float* ad0 = (const float*)d_in[8];
    const float* ad1 = (const float*)d_in[9];
    const float* ad2 = (const float*)d_in[10];
    const float* b0  = (const float*)d_in[11];
    const float* b1  = (const float*)d_in[12];
    const float* b2  = (const float*)d_in[13];
    const float* Wp  = (const float*)d_in[14];
    const float* bp  = (const float*)d_in[15];
    float* out = (float*)d_out;

    char* p = (char*)d_ws;
    auto alloc = [&](size_t bytes) {
        char* r = p;
        p += (bytes + 255) & ~(size_t)255;
        return r;
    };
    ushort* xbf      = (ushort*)alloc((size_t)NN * 64 * 2);   // bf16 input
    uchar*  hf8      = (uchar*)alloc((size_t)NN * HD);        // fp8 gather rows
    ushort* abf      = (ushort*)alloc((size_t)NN * HD * 2);   // aggregate output (bf16)
    ushort* Wt0      = (ushort*)alloc((size_t)64 * 128 * 2);
    ushort* Wt1      = (ushort*)alloc((size_t)128 * 128 * 2);
    ushort* Wt2      = (ushort*)alloc((size_t)128 * 128 * 2);
    float* As        = (float*)alloc((size_t)NN * 4);
    float* Ad        = (float*)alloc((size_t)NN * 4);
    int*   rowptr    = (int*)alloc((size_t)(NN + 1) * 4);
    int*   deg       = (int*)alloc((size_t)NN * 4);
    uint2* stage     = (uint2*)alloc((size_t)NE * 8);         // bucket-grouped (src,dst)
    int*   col       = (int*)alloc((size_t)ET * 4);
    int*   bucketCnt = (int*)alloc((size_t)NB * 16 * 4);      // padded
    int*   bucketCur = (int*)alloc((size_t)NB * 16 * 4);      // padded
    int*   bucketOff = (int*)alloc((size_t)(NB + 1) * 4);
    int*   partials  = (int*)alloc(1024 * 4);
    float* g         = (float*)alloc(512);

    // converts (independent of CSR)
    convx_kernel<<<(NN * 16 + 255) / 256, 256, 0, stream>>>(x, xbf, NN * 16);
    convw_kernel<64><<<(64 * 128 + 255) / 256, 256, 0, stream>>>(W0, Wt0);
    convw_kernel<128><<<(128 * 128 + 255) / 256, 256, 0, stream>>>(W1, Wt1);
    convw_kernel<128><<<(128 * 128 + 255) / 256, 256, 0, stream>>>(W2, Wt2);

    // CSR build (bucketed two-phase)
    hipMemsetAsync(bucketCnt, 0, (size_t)NB * 16 * 4, stream);
    p1a_hist_kernel<<<EB, 256, 0, stream>>>(ei + NE, bucketCnt);
    p1b_bscan_kernel<<<1, 1024, 0, stream>>>(bucketCnt, bucketOff, bucketCur);
    p1c_part_kernel<<<EB, 256, 0, stream>>>(ei, bucketCur, stage);
    p2a_deg_kernel<<<NB, 256, 0, stream>>>(stage, bucketOff, deg);
    const int SB = (NN + 1023) / 1024;  // 98
    scan1_kernel<<<SB, 1024, 0, stream>>>(deg, rowptr, partials);
    scan2_kernel<<<1, 128, 0, stream>>>(partials, SB);
    scan3_kernel<<<SB, 1024, 0, stream>>>(rowptr, partials);
    p2c_place_kernel<<<NB, 256, 0, stream>>>(stage, bucketOff, rowptr, col);

    const int GB = (NN + 127) / 128;  // 782
    const int AB = NN / 8;            // 12500 (exact)

    // layer 0
    gemm_mfma_kernel<64><<<GB, 256, 0, stream>>>(xbf, Wt0, as0, ad0, hf8, As, Ad);
    aggregate_kernel<<<AB, 256, 0, stream>>>(hf8, As, Ad, rowptr, col, b0, abf, 1);
    // layer 1
    gemm_mfma_kernel<128><<<GB, 256, 0, stream>>>(abf, Wt1, as1, ad1, hf8, As, Ad);
    aggregate_kernel<<<AB, 256, 0, stream>>>(hf8, As, Ad, rowptr, col, b1, abf, 1);
    // layer 2
    gemm_mfma_kernel<128><<<GB, 256, 0, stream>>>(abf, Wt2, as2, ad2, hf8, As, Ad);
    aggregate_kernel<<<AB, 256, 0, stream>>>(hf8, As, Ad, rowptr, col, b2, abf, 0);

    // readout
    hipMemsetAsync(g, 0, 128 * 4, stream);
    sum_kernel<<<256, 256, 0, stream>>>(abf, g);
    finalize_kernel<<<1, 128, 0, stream>>>(g, Wp, bp, out);
}

// Round 6
// 358.166 us; speedup vs baseline: 2.6350x; 1.0392x over previous
//
#include <hip/hip_runtime.h>

// GAT 3-layer, N=100000 nodes, E=1.6M edges (+N self loops), Fin=64, H=128.
// CSR build: coarse-bucketed (1024 nodes/bucket) two-phase counting sort.
// Per layer: bf16 MFMA GEMM (fp8-e4m3 h for the gather, fp32 alpha epilogue)
//   -> per-node (2 nodes/wave) online-softmax aggregate (fp8 gather, bf16 out).

#define NN 100000
#define NE 1600000
#define ET (NE + NN)   // edges + self loops
#define HD 128
#define NCB 98         // coarse buckets = ceil(NN / 1024)
#define EB 782         // edge-partition blocks = ceil(NE / 2048)

typedef unsigned int uint;
typedef unsigned short ushort;
typedef unsigned char uchar;
typedef __attribute__((ext_vector_type(8))) short bf16x8;
typedef __attribute__((ext_vector_type(8))) ushort u16x8;
typedef __attribute__((ext_vector_type(4))) float f32x4;
typedef __attribute__((ext_vector_type(2))) float f32x2;

__device__ __forceinline__ ushort f2b(float f) {   // fp32 -> bf16 RTN-even
    uint u = __float_as_uint(f);
    return (ushort)((u + 0x7fffu + ((u >> 16) & 1u)) >> 16);
}
__device__ __forceinline__ float b2f_lo(uint v) { return __uint_as_float(v << 16); }
__device__ __forceinline__ float b2f_hi(uint v) { return __uint_as_float(v & 0xffff0000u); }
__device__ __forceinline__ uchar f2fp8(float f) {  // fp32 -> fp8 e4m3 (OCP), RNE+sat
    return (uchar)(__builtin_amdgcn_cvt_pk_fp8_f32(f, f, 0, false) & 0xff);
}

// ---------------- converts ----------------

__global__ __launch_bounds__(256) void convx_kernel(const float* __restrict__ X,
                                                    ushort* __restrict__ Xb, int total4) {
    int i = blockIdx.x * 256 + threadIdx.x;
    if (i >= total4) return;
    float4 v = *(const float4*)&X[(size_t)i * 4];
    ushort4 o = {f2b(v.x), f2b(v.y), f2b(v.z), f2b(v.w)};
    *(ushort4*)&Xb[(size_t)i * 4] = o;
}

template <int K>
__global__ __launch_bounds__(256) void convw_kernel(const float* __restrict__ W,
                                                    ushort* __restrict__ Wt) {
    int i = blockIdx.x * 256 + threadIdx.x;
    if (i >= K * 128) return;
    int n = i / K, k = i - n * K;
    Wt[n * K + k] = f2b(W[k * 128 + n]);   // transpose: Wt[n][k] = W[k][n]
}

// ---------------- CSR build: coarse-bucketed two-phase counting sort ----------------
// bucket b = dst >> 10 (1024 nodes per bucket, NCB=98).

// P1a: global bucket histogram (LDS hist, batched global atomics on padded counters)
__global__ __launch_bounds__(256) void p1a_hist_kernel(const int* __restrict__ eidst,
                                                       int* __restrict__ bucketCnt) {
    __shared__ int cnt[NCB];
    const int t = threadIdx.x;
    if (t < NCB) cnt[t] = 0;
    __syncthreads();
    const int base = blockIdx.x * 2048;
    #pragma unroll
    for (int i = 0; i < 8; ++i) {
        int e = base + t + i * 256;
        if (e < NE) atomicAdd(&cnt[eidst[e] >> 10], 1);
    }
    __syncthreads();
    if (t < NCB) {
        int v = cnt[t];
        if (v) atomicAdd(&bucketCnt[t << 4], v);
    }
}

// P1b: exclusive scan of bucket counts -> off[NCB+1]; init cur (padded) = off
__global__ void p1b_bscan_kernel(const int* __restrict__ bucketCnt,
                                 int* __restrict__ off,
                                 int* __restrict__ cur) {
    __shared__ int s[128];
    const int t = threadIdx.x;
    int v = (t < NCB) ? bucketCnt[t << 4] : 0;
    s[t] = v;
    __syncthreads();
    #pragma unroll
    for (int o = 1; o < 128; o <<= 1) {
        int add = (t >= o) ? s[t - o] : 0;
        __syncthreads();
        s[t] += add;
        __syncthreads();
    }
    if (t < NCB) {
        int ex = s[t] - v;
        off[t] = ex;
        cur[t << 4] = ex;
    }
    if (t == 127) off[NCB] = s[t];
}

// P1c: partition edges into bucket-grouped (src,dst) pairs.
// 98 buckets -> per block-bucket runs ~21 edges (168B) -> near-full-line writebacks.
__global__ __launch_bounds__(256) void p1c_part_kernel(const int* __restrict__ ei,
                                                       int* __restrict__ cur,
                                                       uint2* __restrict__ stage) {
    __shared__ int cnt[NCB];
    const int t = threadIdx.x;
    if (t < NCB) cnt[t] = 0;
    __syncthreads();
    const int base = blockIdx.x * 2048;
    int src[8], dst[8];
    #pragma unroll
    for (int i = 0; i < 8; ++i) {
        int e = base + t + i * 256;
        if (e < NE) {
            src[i] = ei[e];
            dst[i] = ei[NE + e];
            atomicAdd(&cnt[dst[i] >> 10], 1);
        } else dst[i] = -1;
    }
    __syncthreads();
    if (t < NCB) {
        int v = cnt[t];
        if (v) cnt[t] = atomicAdd(&cur[t << 4], v);   // cnt becomes this block's base
    }
    __syncthreads();
    #pragma unroll
    for (int i = 0; i < 8; ++i) {
        if (dst[i] >= 0) {
            int pos = atomicAdd(&cnt[dst[i] >> 10], 1);
            stage[pos] = (uint2){(uint)src[i], (uint)dst[i]};
        }
    }
}

// P2a: per-bucket degree count (contiguous stage window, LDS hist over 1024 nodes)
__global__ __launch_bounds__(256) void p2a_deg_kernel(const uint2* __restrict__ stage,
                                                      const int* __restrict__ off,
                                                      int* __restrict__ deg) {
    __shared__ int d[1024];
    const int t = threadIdx.x;
    const int b = blockIdx.x;
    for (int i = t; i < 1024; i += 256) d[i] = 0;
    __syncthreads();
    const int s0 = off[b], s1 = off[b + 1];
    for (int i = s0 + t; i < s1; i += 256)
        atomicAdd(&d[stage[i].y & 1023], 1);
    __syncthreads();
    for (int i = t; i < 1024; i += 256) {
        int node = (b << 10) + i;
        if (node < NN) deg[node] = d[i];
    }
}

__global__ __launch_bounds__(1024) void scan1_kernel(const int* __restrict__ deg,
                                                     int* __restrict__ rowptr,
                                                     int* __restrict__ partials) {
    __shared__ int s[1024];
    int t = threadIdx.x;
    int i = blockIdx.x * 1024 + t;
    int v = (i < NN) ? (deg[i] + 1) : 0;   // +1 = self loop
    s[t] = v;
    __syncthreads();
    #pragma unroll
    for (int off = 1; off < 1024; off <<= 1) {
        int add = (t >= off) ? s[t - off] : 0;
        __syncthreads();
        s[t] += add;
        __syncthreads();
    }
    if (i < NN) rowptr[i + 1] = s[t];
    if (t == 1023) partials[blockIdx.x] = s[t];
}

__global__ void scan2_kernel(int* __restrict__ partials, int nb) {
    __shared__ int s[128];
    int t = threadIdx.x;
    int v = (t < nb) ? partials[t] : 0;
    s[t] = v;
    __syncthreads();
    #pragma unroll
    for (int off = 1; off < 128; off <<= 1) {
        int add = (t >= off) ? s[t - off] : 0;
        __syncthreads();
        s[t] += add;
        __syncthreads();
    }
    if (t < nb) partials[t] = s[t] - v;  // exclusive offsets
}

__global__ __launch_bounds__(1024) void scan3_kernel(int* __restrict__ rowptr,
                                                     const int* __restrict__ partials) {
    int t = threadIdx.x;
    int i = blockIdx.x * 1024 + t;
    if (i < NN) {
        rowptr[i + 1] += partials[blockIdx.x];
        if (i == 0) rowptr[0] = 0;
    }
}

// P2c: per-bucket placement (col writes land in a block-exclusive contiguous window)
__global__ __launch_bounds__(256) void p2c_place_kernel(const uint2* __restrict__ stage,
                                                        const int* __restrict__ off,
                                                        const int* __restrict__ rowptr,
                                                        int* __restrict__ col) {
    __shared__ int cur[1024];
    const int t = threadIdx.x;
    const int b = blockIdx.x;
    for (int i = t; i < 1024; i += 256) {
        int node = (b << 10) + i;
        if (node < NN) {
            cur[i] = rowptr[node];
            col[rowptr[node + 1] - 1] = node;   // self loop -> last slot
        } else cur[i] = 0;
    }
    __syncthreads();
    const int s0 = off[b], s1 = off[b + 1];
    for (int i = s0 + t; i < s1; i += 256) {
        uint2 p = stage[i];
        int pos = atomicAdd(&cur[p.y & 1023], 1);
        col[pos] = (int)p.x;
    }
}

// ---------------- MFMA GEMM: Hf8 = fp8(Xb @ W), fused fp32 alpha epilogue ----------------
// 256 thr = 4 waves; block = 128 rows x 128 cols; wave = 32 rows.
// mfma_f32_16x16x32_bf16 C/D: col=l&15, row=(l>>4)*4+j  [verified m89/m91].

template <int K>
__global__ __launch_bounds__(256) void gemm_mfma_kernel(const ushort* __restrict__ Xb,
                                                        const ushort* __restrict__ Wt,
                                                        const float* __restrict__ a_src,
                                                        const float* __restrict__ a_dst,
                                                        uchar* __restrict__ Hf8,
                                                        float* __restrict__ As,
                                                        float* __restrict__ Ad) {
    const int t = threadIdx.x;
    const int w = t >> 6;
    const int l = t & 63;
    const int c16 = l & 15;
    const int kg = l >> 4;
    const int rowBase = blockIdx.x * 128 + w * 32;

    f32x4 acc[2][8] = {};

    const int r0c = min(rowBase + c16, NN - 1);
    const int r1c = min(rowBase + 16 + c16, NN - 1);

    #pragma unroll
    for (int ks = 0; ks < K / 32; ++ks) {
        const int k0 = ks * 32 + kg * 8;
        bf16x8 a0 = *(const bf16x8*)(Xb + (size_t)r0c * K + k0);
        bf16x8 a1 = *(const bf16x8*)(Xb + (size_t)r1c * K + k0);
        #pragma unroll
        for (int n = 0; n < 8; ++n) {
            bf16x8 b = *(const bf16x8*)(Wt + (size_t)(n * 16 + c16) * K + k0);
            acc[0][n] = __builtin_amdgcn_mfma_f32_16x16x32_bf16(a0, b, acc[0][n], 0, 0, 0);
            acc[1][n] = __builtin_amdgcn_mfma_f32_16x16x32_bf16(a1, b, acc[1][n], 0, 0, 0);
        }
    }

    float avs[8], avd[8];
    #pragma unroll
    for (int n = 0; n < 8; ++n) {
        avs[n] = a_src[n * 16 + c16];
        avd[n] = a_dst[n * 16 + c16];
    }

    #pragma unroll
    for (int m = 0; m < 2; ++m) {
        #pragma unroll
        for (int j = 0; j < 4; ++j) {
            const int gr = rowBase + m * 16 + kg * 4 + j;
            const bool ok = (gr < NN);
            if (ok) {
                #pragma unroll
                for (int n = 0; n < 8; ++n)
                    Hf8[(size_t)gr * HD + n * 16 + c16] = f2fp8(acc[m][n][j]);
            }
            float ps = 0.f, pd = 0.f;
            #pragma unroll
            for (int n = 0; n < 8; ++n) {
                ps = fmaf(acc[m][n][j], avs[n], ps);
                pd = fmaf(acc[m][n][j], avd[n], pd);
            }
            #pragma unroll
            for (int off = 8; off >= 1; off >>= 1) {
                ps += __shfl_xor(ps, off);
                pd += __shfl_xor(pd, off);
            }
            if (ok && c16 == 0) { As[gr] = ps; Ad[gr] = pd; }
        }
    }
}

// ---------------- per-dst online softmax + aggregate ----------------
// 2 nodes per wave (32 lanes each); per node: 2 groups x 16 lanes; 4 edges per group
// per iter -> 8 independent fp8-row gather streams per wave.

__global__ __launch_bounds__(256) void aggregate_kernel(const uchar* __restrict__ h8,
                                                        const float* __restrict__ As,
                                                        const float* __restrict__ Ad,
                                                        const int* __restrict__ rowptr,
                                                        const int* __restrict__ col,
                                                        const float* __restrict__ bias,
                                                        ushort* __restrict__ out,
                                                        int relu) {
    const int lane  = threadIdx.x & 63;
    const int sub   = lane & 31;        // lane within node
    const int g2    = sub >> 4;         // edge-group 0/1
    const int q     = sub & 15;         // feature lane -> feats [q*8, q*8+8)
    const int lbase = lane & 32;        // node-half base for shfl
    const int node  = blockIdx.x * 8 + ((threadIdx.x >> 6) << 1) + (lane >> 5);
    // grid is exact: 12500 * 8 == NN

    const int start = rowptr[node];
    const int end   = rowptr[node + 1];
    const float ad_i = Ad[node];

    float m = -1e30f;
    float denom = 0.f;
    float acc[8] = {};

    for (int base = start; base < end; base += 32) {
        const int cnt = min(32, end - base);
        int   sc = 0;
        float e  = -1e30f;
        if (sub < cnt) {
            sc = col[base + sub];
            float a = As[sc] + ad_i;
            e = (a > 0.f) ? a : 0.2f * a;       // leaky_relu 0.2
        }
        float cmax = e;
        #pragma unroll
        for (int off = 16; off >= 1; off >>= 1) cmax = fmaxf(cmax, __shfl_xor(cmax, off));
        // branchless online rescale (s==0 on first chunk, ==1 when max unchanged)
        float s = __expf(fminf(m - cmax, 0.f));
        m = fmaxf(m, cmax);
        #pragma unroll
        for (int i = 0; i < 8; ++i) acc[i] *= s;
        denom *= s;

        float w = (sub < cnt) ? __expf(e - m) : 0.f;
        denom += w;

        for (int jj = 0; jj < cnt; jj += 8) {
            const int i0 = lbase | (jj + 4 * g2);
            float wv[4]; int sv[4];
            #pragma unroll
            for (int u = 0; u < 4; ++u) {
                wv[u] = __shfl(w, i0 + u);
                sv[u] = __shfl(sc, i0 + u);
            }
            uint2 vv[4];
            #pragma unroll
            for (int u = 0; u < 4; ++u)
                vv[u] = *(const uint2*)(h8 + (size_t)sv[u] * HD + q * 8);
            #pragma unroll
            for (int u = 0; u < 4; ++u) {
                f32x2 p0 = __builtin_amdgcn_cvt_pk_f32_fp8(vv[u].x, false);
                f32x2 p1 = __builtin_amdgcn_cvt_pk_f32_fp8(vv[u].x, true);
                f32x2 p2 = __builtin_amdgcn_cvt_pk_f32_fp8(vv[u].y, false);
                f32x2 p3 = __builtin_amdgcn_cvt_pk_f32_fp8(vv[u].y, true);
                acc[0] = fmaf(wv[u], p0.x, acc[0]); acc[1] = fmaf(wv[u], p0.y, acc[1]);
                acc[2] = fmaf(wv[u], p1.x, acc[2]); acc[3] = fmaf(wv[u], p1.y, acc[3]);
                acc[4] = fmaf(wv[u], p2.x, acc[4]); acc[5] = fmaf(wv[u], p2.y, acc[5]);
                acc[6] = fmaf(wv[u], p3.x, acc[6]); acc[7] = fmaf(wv[u], p3.y, acc[7]);
            }
        }
    }

    // cross-group feature reduce (xor 16 combines the node's two groups)
    #pragma unroll
    for (int i = 0; i < 8; ++i) acc[i] += __shfl_xor(acc[i], 16);
    #pragma unroll
    for (int off = 16; off >= 1; off >>= 1) denom += __shfl_xor(denom, off);

    if (g2 == 0) {
        float inv = 1.0f / denom;
        float4 bv0 = *(const float4*)&bias[q * 8];
        float4 bv1 = *(const float4*)&bias[q * 8 + 4];
        float bb[8] = {bv0.x, bv0.y, bv0.z, bv0.w, bv1.x, bv1.y, bv1.z, bv1.w};
        u16x8 o;
        #pragma unroll
        for (int i = 0; i < 8; ++i) {
            float v = fmaf(acc[i], inv, bb[i]);
            if (relu) v = fmaxf(v, 0.f);
            o[i] = f2b(v);
        }
        *(u16x8*)&out[(size_t)node * HD + q * 8] = o;
    }
}

// ---------------- readout ----------------

__global__ __launch_bounds__(256) void sum_kernel(const ushort* __restrict__ h,
                                                  float* __restrict__ g) {
    int t = threadIdx.x;
    int wave = t >> 6, lane = t & 63;
    float sx = 0.f, sy = 0.f;
    for (int r = blockIdx.x * 4 + wave; r < NN; r += gridDim.x * 4) {
        uint v = *(const uint*)&h[(size_t)r * HD + lane * 2];
        sx += b2f_lo(v); sy += b2f_hi(v);
    }
    __shared__ float sm[512];
    sm[wave * 128 + lane * 2]     = sx;
    sm[wave * 128 + lane * 2 + 1] = sy;
    __syncthreads();
    if (t < 128) {
        float s = sm[t] + sm[128 + t] + sm[256 + t] + sm[384 + t];
        atomicAdd(&g[t], s);
    }
}

__global__ void finalize_kernel(const float* __restrict__ g, const float* __restrict__ Wp,
                                const float* __restrict__ bp, float* __restrict__ out) {
    int t = threadIdx.x;
    float v = g[t] * Wp[t];
    #pragma unroll
    for (int m = 32; m >= 1; m >>= 1) v += __shfl_xor(v, m);
    __shared__ float red[2];
    if ((t & 63) == 0) red[t >> 6] = v;
    __syncthreads();
    if (t == 0) out[0] = (red[0] + red[1]) * (1.0f / NN) + bp[0];
}

// ---------------- launch ----------------

extern "C" void kernel_launch(void* const* d_in, const int* in_sizes, int n_in,
                              void* d_out, int out_size, void* d_ws, size_t ws_size,
                              hipStream_t stream) {
    const float* x   = (const float*)d_in[0];
    const int*   ei  = (const int*)d_in[1];
    const float* W0  = (const float*)d_in[2];
    const float* W1  = (const float*)d_in[3];
    const float* W2  = (const float*)d_in[4];
    const float* as0 = (const float*)d_in[5];
    const float* as1 = (const float*)d_in[6];
    const float* as2 = (const float*)d_in[7];
    const float* ad0 = (const float*)d_in[8];
    const float* ad1 = (const float*)d_in[9];
    const float* ad2 = (const float*)d_in[10];
    const float* b0  = (const float*)d_in[11];
    const float* b1  = (const float*)d_in[12];
    const float* b2  = (const float*)d_in[13];
    const float* Wp  = (const float*)d_in[14];
    const float* bp  = (const float*)d_in[15];
    float* out = (float*)d_out;

    char* p = (char*)d_ws;
    auto alloc = [&](size_t bytes) {
        char* r = p;
        p += (bytes + 255) & ~(size_t)255;
        return r;
    };
    ushort* xbf      = (ushort*)alloc((size_t)NN * 64 * 2);   // bf16 input
    uchar*  hf8      = (uchar*)alloc((size_t)NN * HD);        // fp8 gather rows
    ushort* abf      = (ushort*)alloc((size_t)NN * HD * 2);   // aggregate output (bf16)
    ushort* Wt0      = (ushort*)alloc((size_t)64 * 128 * 2);
    ushort* Wt1      = (ushort*)alloc((size_t)128 * 128 * 2);
    ushort* Wt2      = (ushort*)alloc((size_t)128 * 128 * 2);
    float* As        = (float*)alloc((size_t)NN * 4);
    float* Ad        = (float*)alloc((size_t)NN * 4);
    int*   rowptr    = (int*)alloc((size_t)(NN + 1) * 4);
    int*   deg       = (int*)alloc((size_t)NN * 4);
    uint2* stage     = (uint2*)alloc((size_t)NE * 8);         // bucket-grouped (src,dst)
    int*   col       = (int*)alloc((size_t)ET * 4);
    int*   bucketCnt = (int*)alloc((size_t)NCB * 16 * 4);     // padded
    int*   bucketCur = (int*)alloc((size_t)NCB * 16 * 4);     // padded
    int*   bucketOff = (int*)alloc((size_t)(NCB + 1) * 4);
    int*   partials  = (int*)alloc(1024 * 4);
    float* g         = (float*)alloc(512);

    // converts (independent of CSR)
    convx_kernel<<<(NN * 16 + 255) / 256, 256, 0, stream>>>(x, xbf, NN * 16);
    convw_kernel<64><<<(64 * 128 + 255) / 256, 256, 0, stream>>>(W0, Wt0);
    convw_kernel<128><<<(128 * 128 + 255) / 256, 256, 0, stream>>>(W1, Wt1);
    convw_kernel<128><<<(128 * 128 + 255) / 256, 256, 0, stream>>>(W2, Wt2);

    // CSR build (coarse-bucketed two-phase)
    hipMemsetAsync(bucketCnt, 0, (size_t)NCB * 16 * 4, stream);
    p1a_hist_kernel<<<EB, 256, 0, stream>>>(ei + NE, bucketCnt);
    p1b_bscan_kernel<<<1, 128, 0, stream>>>(bucketCnt, bucketOff, bucketCur);
    p1c_part_kernel<<<EB, 256, 0, stream>>>(ei, bucketCur, stage);
    p2a_deg_kernel<<<NCB, 256, 0, stream>>>(stage, bucketOff, deg);
    const int SB = (NN + 1023) / 1024;  // 98
    scan1_kernel<<<SB, 1024, 0, stream>>>(deg, rowptr, partials);
    scan2_kernel<<<1, 128, 0, stream>>>(partials, SB);
    scan3_kernel<<<SB, 1024, 0, stream>>>(rowptr, partials);
    p2c_place_kernel<<<NCB, 256, 0, stream>>>(stage, bucketOff, rowptr, col);

    const int GB = (NN + 127) / 128;  // 782
    const int AB = NN / 8;            // 12500 (exact)

    // layer 0
    gemm_mfma_kernel<64><<<GB, 256, 0, stream>>>(xbf, Wt0, as0, ad0, hf8, As, Ad);
    aggregate_kernel<<<AB, 256, 0, stream>>>(hf8, As, Ad, rowptr, col, b0, abf, 1);
    // layer 1
    gemm_mfma_kernel<128><<<GB, 256, 0, stream>>>(abf, Wt1, as1, ad1, hf8, As, Ad);
    aggregate_kernel<<<AB, 256, 0, stream>>>(hf8, As, Ad, rowptr, col, b1, abf, 1);
    // layer 2
    gemm_mfma_kernel<128><<<GB, 256, 0, stream>>>(abf, Wt2, as2, ad2, hf8, As, Ad);
    aggregate_kernel<<<AB, 256, 0, stream>>>(hf8, As, Ad, rowptr, col, b2, abf, 0);

    // readout
    hipMemsetAsync(g, 0, 128 * 4, stream);
    sum_kernel<<<256, 256, 0, stream>>>(abf, g);
    finalize_kernel<<<1, 128, 0, stream>>>(g, Wp, bp, out);
}

// Round 7
// 334.432 us; speedup vs baseline: 2.8220x; 1.0710x over previous
//
#include <hip/hip_runtime.h>

// GAT 3-layer, N=100000 nodes, E=1.6M edges (+N self loops), Fin=64, H=128.
// Fused pipeline (12 dispatches):
//   memset bucketCnt -> K1{converts + bucket hist + zero g} -> p1b scan ->
//   K3{edge partition || gemm0} -> p2{deg+scan+rowptr+place fused} ->
//   3x (gemm -> aggregate) -> sum -> finalize.

#define NN 100000
#define NE 1600000
#define ET (NE + NN)   // edges + self loops
#define HD 128
#define NCB 98         // coarse buckets = ceil(NN / 1024)
#define EB 782         // edge-partition blocks = ceil(NE / 2048)
#define GB 782         // gemm blocks = ceil(NN / 128)
#define K1_BX 6250     // convx blocks (NN*16 float4 / 256)
#define K1_BW0 32
#define K1_BW1 64
#define K1_BW2 64

typedef unsigned int uint;
typedef unsigned short ushort;
typedef unsigned char uchar;
typedef __attribute__((ext_vector_type(8))) short bf16x8;
typedef __attribute__((ext_vector_type(8))) ushort u16x8;
typedef __attribute__((ext_vector_type(4))) float f32x4;
typedef __attribute__((ext_vector_type(2))) float f32x2;

__device__ __forceinline__ ushort f2b(float f) {   // fp32 -> bf16 RTN-even
    uint u = __float_as_uint(f);
    return (ushort)((u + 0x7fffu + ((u >> 16) & 1u)) >> 16);
}
__device__ __forceinline__ float b2f_lo(uint v) { return __uint_as_float(v << 16); }
__device__ __forceinline__ float b2f_hi(uint v) { return __uint_as_float(v & 0xffff0000u); }
__device__ __forceinline__ uchar f2fp8(float f) {  // fp32 -> fp8 e4m3 (OCP), RNE+sat
    return (uchar)(__builtin_amdgcn_cvt_pk_fp8_f32(f, f, 0, false) & 0xff);
}

// ---------------- K1: converts + bucket histogram + zero g ----------------

__global__ __launch_bounds__(256) void k1_fused_kernel(
        const float* __restrict__ x, ushort* __restrict__ xbf,
        const float* __restrict__ W0, ushort* __restrict__ Wt0,
        const float* __restrict__ W1, ushort* __restrict__ Wt1,
        const float* __restrict__ W2, ushort* __restrict__ Wt2,
        const int* __restrict__ eidst, int* __restrict__ bucketCnt,
        float* __restrict__ g) {
    __shared__ int cnt[NCB];
    const int t = threadIdx.x;
    int b = blockIdx.x;
    if (b < K1_BX) {                       // x -> bf16
        if (b == 0 && t < 128) g[t] = 0.f;
        int i = b * 256 + t;
        float4 v = *(const float4*)&x[(size_t)i * 4];
        ushort4 o = {f2b(v.x), f2b(v.y), f2b(v.z), f2b(v.w)};
        *(ushort4*)&xbf[(size_t)i * 4] = o;
        return;
    }
    b -= K1_BX;
    if (b < K1_BW0) {                      // W0 -> Wt0 (transposed bf16)
        int i = b * 256 + t;
        int n = i >> 6, k = i & 63;
        Wt0[n * 64 + k] = f2b(W0[k * 128 + n]);
        return;
    }
    b -= K1_BW0;
    if (b < K1_BW1) {
        int i = b * 256 + t;
        int n = i >> 7, k = i & 127;
        Wt1[n * 128 + k] = f2b(W1[k * 128 + n]);
        return;
    }
    b -= K1_BW1;
    if (b < K1_BW2) {
        int i = b * 256 + t;
        int n = i >> 7, k = i & 127;
        Wt2[n * 128 + k] = f2b(W2[k * 128 + n]);
        return;
    }
    b -= K1_BW2;                           // bucket histogram over dst
    if (t < NCB) cnt[t] = 0;
    __syncthreads();
    const int base = b * 2048;
    #pragma unroll
    for (int i = 0; i < 8; ++i) {
        int e = base + t + i * 256;
        if (e < NE) atomicAdd(&cnt[eidst[e] >> 10], 1);
    }
    __syncthreads();
    if (t < NCB) {
        int v = cnt[t];
        if (v) atomicAdd(&bucketCnt[t << 4], v);
    }
}

// ---------------- p1b: exclusive scan of bucket counts ----------------

__global__ void p1b_bscan_kernel(const int* __restrict__ bucketCnt,
                                 int* __restrict__ off,
                                 int* __restrict__ cur) {
    __shared__ int s[128];
    const int t = threadIdx.x;
    int v = (t < NCB) ? bucketCnt[t << 4] : 0;
    s[t] = v;
    __syncthreads();
    #pragma unroll
    for (int o = 1; o < 128; o <<= 1) {
        int add = (t >= o) ? s[t - o] : 0;
        __syncthreads();
        s[t] += add;
        __syncthreads();
    }
    if (t < NCB) {
        int ex = s[t] - v;
        off[t] = ex;
        cur[t << 4] = ex;
    }
    if (t == 127) off[NCB] = s[t];
}

// ---------------- MFMA GEMM body: Hf8 = fp8(Xb @ W), fused fp32 alpha epilogue ----------------
// 256 thr = 4 waves; block = 128 rows x 128 cols; wave = 32 rows.
// mfma_f32_16x16x32_bf16 C/D: col=l&15, row=(l>>4)*4+j  [verified m89/m91].

template <int K>
__device__ __forceinline__ void gemm_body(int bid,
                                          const ushort* __restrict__ Xb,
                                          const ushort* __restrict__ Wt,
                                          const float* __restrict__ a_src,
                                          const float* __restrict__ a_dst,
                                          uchar* __restrict__ Hf8,
                                          float* __restrict__ As,
                                          float* __restrict__ Ad) {
    const int t = threadIdx.x;
    const int w = t >> 6;
    const int l = t & 63;
    const int c16 = l & 15;
    const int kg = l >> 4;
    const int rowBase = bid * 128 + w * 32;

    f32x4 acc[2][8] = {};

    const int r0c = min(rowBase + c16, NN - 1);
    const int r1c = min(rowBase + 16 + c16, NN - 1);

    #pragma unroll
    for (int ks = 0; ks < K / 32; ++ks) {
        const int k0 = ks * 32 + kg * 8;
        bf16x8 a0 = *(const bf16x8*)(Xb + (size_t)r0c * K + k0);
        bf16x8 a1 = *(const bf16x8*)(Xb + (size_t)r1c * K + k0);
        #pragma unroll
        for (int n = 0; n < 8; ++n) {
            bf16x8 b = *(const bf16x8*)(Wt + (size_t)(n * 16 + c16) * K + k0);
            acc[0][n] = __builtin_amdgcn_mfma_f32_16x16x32_bf16(a0, b, acc[0][n], 0, 0, 0);
            acc[1][n] = __builtin_amdgcn_mfma_f32_16x16x32_bf16(a1, b, acc[1][n], 0, 0, 0);
        }
    }

    float avs[8], avd[8];
    #pragma unroll
    for (int n = 0; n < 8; ++n) {
        avs[n] = a_src[n * 16 + c16];
        avd[n] = a_dst[n * 16 + c16];
    }

    #pragma unroll
    for (int m = 0; m < 2; ++m) {
        #pragma unroll
        for (int j = 0; j < 4; ++j) {
            const int gr = rowBase + m * 16 + kg * 4 + j;
            const bool ok = (gr < NN);
            if (ok) {
                #pragma unroll
                for (int n = 0; n < 8; ++n)
                    Hf8[(size_t)gr * HD + n * 16 + c16] = f2fp8(acc[m][n][j]);
            }
            float ps = 0.f, pd = 0.f;
            #pragma unroll
            for (int n = 0; n < 8; ++n) {
                ps = fmaf(acc[m][n][j], avs[n], ps);
                pd = fmaf(acc[m][n][j], avd[n], pd);
            }
            #pragma unroll
            for (int off = 8; off >= 1; off >>= 1) {
                ps += __shfl_xor(ps, off);
                pd += __shfl_xor(pd, off);
            }
            if (ok && c16 == 0) { As[gr] = ps; Ad[gr] = pd; }
        }
    }
}

template <int K>
__global__ __launch_bounds__(256) void gemm_mfma_kernel(const ushort* __restrict__ Xb,
                                                        const ushort* __restrict__ Wt,
                                                        const float* __restrict__ a_src,
                                                        const float* __restrict__ a_dst,
                                                        uchar* __restrict__ Hf8,
                                                        float* __restrict__ As,
                                                        float* __restrict__ Ad) {
    gemm_body<K>(blockIdx.x, Xb, Wt, a_src, a_dst, Hf8, As, Ad);
}

// ---------------- K3: edge partition (packed stage) || gemm layer-0 ----------------

__global__ __launch_bounds__(256) void k3_part_gemm0_kernel(
        const int* __restrict__ ei, int* __restrict__ cur, uint* __restrict__ stage,
        const ushort* __restrict__ xbf, const ushort* __restrict__ Wt0,
        const float* __restrict__ as0, const float* __restrict__ ad0,
        uchar* __restrict__ hf8, float* __restrict__ As, float* __restrict__ Ad) {
    if (blockIdx.x < EB) {
        __shared__ int cnt[NCB];
        const int t = threadIdx.x;
        if (t < NCB) cnt[t] = 0;
        __syncthreads();
        const int base = blockIdx.x * 2048;
        int src[8], dst[8];
        #pragma unroll
        for (int i = 0; i < 8; ++i) {
            int e = base + t + i * 256;
            if (e < NE) {
                src[i] = ei[e];
                dst[i] = ei[NE + e];
                atomicAdd(&cnt[dst[i] >> 10], 1);
            } else dst[i] = -1;
        }
        __syncthreads();
        if (t < NCB) {
            int v = cnt[t];
            if (v) cnt[t] = atomicAdd(&cur[t << 4], v);   // block's base in bucket
        }
        __syncthreads();
        #pragma unroll
        for (int i = 0; i < 8; ++i) {
            if (dst[i] >= 0) {
                int pos = atomicAdd(&cnt[dst[i] >> 10], 1);
                stage[pos] = ((uint)src[i] << 10) | ((uint)dst[i] & 1023u);
            }
        }
    } else {
        gemm_body<64>(blockIdx.x - EB, xbf, Wt0, as0, ad0, hf8, As, Ad);
    }
}

// ---------------- p2 fused: per-bucket deg count + scan -> rowptr + place ----------------
// bucket b owns nodes [b*1024,(b+1)*1024); edge-array start = off[b] + b*1024 (self loops).

__global__ __launch_bounds__(256) void p2_fused_kernel(const uint* __restrict__ stage,
                                                       const int* __restrict__ off,
                                                       int* __restrict__ rowptr,
                                                       int* __restrict__ col) {
    __shared__ int d[1024];
    __shared__ int ts[256];
    const int t = threadIdx.x, b = blockIdx.x;
    #pragma unroll
    for (int i = t; i < 1024; i += 256) d[i] = 0;
    __syncthreads();
    const int s0 = off[b], s1 = off[b + 1];
    for (int i = s0 + t; i < s1; i += 256) atomicAdd(&d[stage[i] & 1023u], 1);
    __syncthreads();
    int4 a = *(const int4*)&d[t * 4];          // degs of local nodes 4t..4t+3
    int tsum = a.x + a.y + a.z + a.w;
    ts[t] = tsum;
    __syncthreads();
    #pragma unroll
    for (int o = 1; o < 256; o <<= 1) {
        int add = (t >= o) ? ts[t - o] : 0;
        __syncthreads();
        ts[t] += add;
        __syncthreads();
    }
    const int bucketStart = s0 + (b << 10);
    int q0 = ts[t] - tsum;                     // exclusive deg prefix
    int e0 = bucketStart + q0 + t * 4;         // rowptr of node 4t (+li self loops)
    int e1 = e0 + a.x + 1;
    int e2 = e1 + a.y + 1;
    int e3 = e2 + a.z + 1;
    int node0 = (b << 10) + t * 4;
    if (node0 + 3 < NN) {
        rowptr[node0]     = e0;
        rowptr[node0 + 1] = e1;
        rowptr[node0 + 2] = e2;
        rowptr[node0 + 3] = e3;
        col[e0 + a.x] = node0;                 // self loop -> last slot
        col[e1 + a.y] = node0 + 1;
        col[e2 + a.z] = node0 + 2;
        col[e3 + a.w] = node0 + 3;
    } else {
        int ee[4] = {e0, e1, e2, e3};
        int aa[4] = {a.x, a.y, a.z, a.w};
        #pragma unroll
        for (int j = 0; j < 4; ++j)
            if (node0 + j < NN) {
                rowptr[node0 + j] = ee[j];
                col[ee[j] + aa[j]] = node0 + j;
            }
    }
    if (b == NCB - 1 && t == 0) rowptr[NN] = ET;
    *(int4*)&d[t * 4] = (int4){e0, e1, e2, e3};   // becomes the placement cursor
    __syncthreads();
    for (int i = s0 + t; i < s1; i += 256) {
        uint v = stage[i];
        int pos = atomicAdd(&d[v & 1023u], 1);
        col[pos] = (int)(v >> 10);
    }
}

// ---------------- per-dst online softmax + aggregate ----------------
// 2 nodes per wave (32 lanes each); per node: 2 groups x 16 lanes; 4 edges per group
// per iter; f32x2 packed FMA accumulation (v_pk_fma_f32).

__global__ __launch_bounds__(256) void aggregate_kernel(const uchar* __restrict__ h8,
                                                        const float* __restrict__ As,
                                                        const float* __restrict__ Ad,
                                                        const int* __restrict__ rowptr,
                                                        const int* __restrict__ col,
                                                        const float* __restrict__ bias,
                                                        ushort* __restrict__ out,
                                                        int relu) {
    const int lane  = threadIdx.x & 63;
    const int sub   = lane & 31;        // lane within node
    const int g2    = sub >> 4;         // edge-group 0/1
    const int q     = sub & 15;         // feature lane -> feats [q*8, q*8+8)
    const int lbase = lane & 32;        // node-half base for shfl
    const int node  = blockIdx.x * 8 + ((threadIdx.x >> 6) << 1) + (lane >> 5);
    // grid is exact: 12500 * 8 == NN

    const int start = rowptr[node];
    const int end   = rowptr[node + 1];
    const float ad_i = Ad[node];

    float m = -1e30f;
    float denom = 0.f;
    f32x2 acc2[4] = {};

    for (int base = start; base < end; base += 32) {
        const int cnt = min(32, end - base);
        int   sc = 0;
        float e  = -1e30f;
        if (sub < cnt) {
            sc = col[base + sub];
            float a = As[sc] + ad_i;
            e = (a > 0.f) ? a : 0.2f * a;       // leaky_relu 0.2
        }
        float cmax = e;
        #pragma unroll
        for (int off = 16; off >= 1; off >>= 1) cmax = fmaxf(cmax, __shfl_xor(cmax, off));
        // branchless online rescale (s==0 on first chunk, ==1 when max unchanged)
        float s = __expf(fminf(m - cmax, 0.f));
        m = fmaxf(m, cmax);
        f32x2 s2 = {s, s};
        #pragma unroll
        for (int i = 0; i < 4; ++i) acc2[i] *= s2;
        denom *= s;

        float w = (sub < cnt) ? __expf(e - m) : 0.f;
        denom += w;

        for (int jj = 0; jj < cnt; jj += 8) {
            const int i0 = lbase | (jj + 4 * g2);
            float wv[4]; int sv[4];
            #pragma unroll
            for (int u = 0; u < 4; ++u) {
                wv[u] = __shfl(w, i0 + u);
                sv[u] = __shfl(sc, i0 + u);
            }
            uint2 vv[4];
            #pragma unroll
            for (int u = 0; u < 4; ++u)
                vv[u] = *(const uint2*)(h8 + (size_t)sv[u] * HD + q * 8);
            #pragma unroll
            for (int u = 0; u < 4; ++u) {
                f32x2 w2 = {wv[u], wv[u]};
                f32x2 p0 = __builtin_amdgcn_cvt_pk_f32_fp8(vv[u].x, false);
                f32x2 p1 = __builtin_amdgcn_cvt_pk_f32_fp8(vv[u].x, true);
                f32x2 p2 = __builtin_amdgcn_cvt_pk_f32_fp8(vv[u].y, false);
                f32x2 p3 = __builtin_amdgcn_cvt_pk_f32_fp8(vv[u].y, true);
                acc2[0] = __builtin_elementwise_fma(w2, p0, acc2[0]);
                acc2[1] = __builtin_elementwise_fma(w2, p1, acc2[1]);
                acc2[2] = __builtin_elementwise_fma(w2, p2, acc2[2]);
                acc2[3] = __builtin_elementwise_fma(w2, p3, acc2[3]);
            }
        }
    }

    float accf[8];
    #pragma unroll
    for (int i = 0; i < 4; ++i) { accf[2 * i] = acc2[i][0]; accf[2 * i + 1] = acc2[i][1]; }

    // cross-group feature reduce (xor 16 combines the node's two groups)
    #pragma unroll
    for (int i = 0; i < 8; ++i) accf[i] += __shfl_xor(accf[i], 16);
    #pragma unroll
    for (int off = 16; off >= 1; off >>= 1) denom += __shfl_xor(denom, off);

    if (g2 == 0) {
        float inv = 1.0f / denom;
        float4 bv0 = *(const float4*)&bias[q * 8];
        float4 bv1 = *(const float4*)&bias[q * 8 + 4];
        float bb[8] = {bv0.x, bv0.y, bv0.z, bv0.w, bv1.x, bv1.y, bv1.z, bv1.w};
        u16x8 o;
        #pragma unroll
        for (int i = 0; i < 8; ++i) {
            float v = fmaf(accf[i], inv, bb[i]);
            if (relu) v = fmaxf(v, 0.f);
            o[i] = f2b(v);
        }
        *(u16x8*)&out[(size_t)node * HD + q * 8] = o;
    }
}

// ---------------- readout ----------------

__global__ __launch_bounds__(256) void sum_kernel(const ushort* __restrict__ h,
                                                  float* __restrict__ g) {
    int t = threadIdx.x;
    int wave = t >> 6, lane = t & 63;
    float sx = 0.f, sy = 0.f;
    for (int r = blockIdx.x * 4 + wave; r < NN; r += gridDim.x * 4) {
        uint v = *(const uint*)&h[(size_t)r * HD + lane * 2];
        sx += b2f_lo(v); sy += b2f_hi(v);
    }
    __shared__ float sm[512];
    sm[wave * 128 + lane * 2]     = sx;
    sm[wave * 128 + lane * 2 + 1] = sy;
    __syncthreads();
    if (t < 128) {
        float s = sm[t] + sm[128 + t] + sm[256 + t] + sm[384 + t];
        atomicAdd(&g[t], s);
    }
}

__global__ void finalize_kernel(const float* __restrict__ g, const float* __restrict__ Wp,
                                const float* __restrict__ bp, float* __restrict__ out) {
    int t = threadIdx.x;
    float v = g[t] * Wp[t];
    #pragma unroll
    for (int m = 32; m >= 1; m >>= 1) v += __shfl_xor(v, m);
    __shared__ float red[2];
    if ((t & 63) == 0) red[t >> 6] = v;
    __syncthreads();
    if (t == 0) out[0] = (red[0] + red[1]) * (1.0f / NN) + bp[0];
}

// ---------------- launch ----------------

extern "C" void kernel_launch(void* const* d_in, const int* in_sizes, int n_in,
                              void* d_out, int out_size, void* d_ws, size_t ws_size,
                              hipStream_t stream) {
    const float* x   = (const float*)d_in[0];
    const int*   ei  = (const int*)d_in[1];
    const float* W0  = (const float*)d_in[2];
    const float* W1  = (const float*)d_in[3];
    const float* W2  = (const float*)d_in[4];
    const float* as0 = (const float*)d_in[5];
    const float* as1 = (const float*)d_in[6];
    const float* as2 = (const float*)d_in[7];
    const float* ad0 = (const float*)d_in[8];
    const float* ad1 = (const float*)d_in[9];
    const float* ad2 = (const float*)d_in[10];
    const float* b0  = (const float*)d_in[11];
    const float* b1  = (const float*)d_in[12];
    const float* b2  = (const float*)d_in[13];
    const float* Wp  = (const float*)d_in[14];
    const float* bp  = (const float*)d_in[15];
    float* out = (float*)d_out;

    char* p = (char*)d_ws;
    auto alloc = [&](size_t bytes) {
        char* r = p;
        p += (bytes + 255) & ~(size_t)255;
        return r;
    };
    ushort* xbf      = (ushort*)alloc((size_t)NN * 64 * 2);   // bf16 input
    uchar*  hf8      = (uchar*)alloc((size_t)NN * HD);        // fp8 gather rows
    ushort* abf      = (ushort*)alloc((size_t)NN * HD * 2);   // aggregate output (bf16)
    ushort* Wt0      = (ushort*)alloc((size_t)64 * 128 * 2);
    ushort* Wt1      = (ushort*)alloc((size_t)128 * 128 * 2);
    ushort* Wt2      = (ushort*)alloc((size_t)128 * 128 * 2);
    float* As        = (float*)alloc((size_t)NN * 4);
    float* Ad        = (float*)alloc((size_t)NN * 4);
    int*   rowptr    = (int*)alloc((size_t)(NN + 1) * 4);
    uint*  stage     = (uint*)alloc((size_t)NE * 4);          // packed (src<<10)|dstLocal
    int*   col       = (int*)alloc((size_t)ET * 4);
    int*   bucketCnt = (int*)alloc((size_t)NCB * 16 * 4);     // padded
    int*   bucketCur = (int*)alloc((size_t)NCB * 16 * 4);     // padded
    int*   bucketOff = (int*)alloc((size_t)(NCB + 1) * 4);
    float* g         = (float*)alloc(512);

    hipMemsetAsync(bucketCnt, 0, (size_t)NCB * 16 * 4, stream);

    // K1: all converts + bucket histogram + zero g
    const int K1B = K1_BX + K1_BW0 + K1_BW1 + K1_BW2 + EB;  // 7192
    k1_fused_kernel<<<K1B, 256, 0, stream>>>(x, xbf, W0, Wt0, W1, Wt1, W2, Wt2,
                                             ei + NE, bucketCnt, g);
    p1b_bscan_kernel<<<1, 128, 0, stream>>>(bucketCnt, bucketOff, bucketCur);
    // K3: edge partition || layer-0 gemm (independent work, one dispatch)
    k3_part_gemm0_kernel<<<EB + GB, 256, 0, stream>>>(ei, bucketCur, stage,
                                                      xbf, Wt0, as0, ad0, hf8, As, Ad);
    // p2: deg count + LDS scan -> rowptr + self loops + placement
    p2_fused_kernel<<<NCB, 256, 0, stream>>>(stage, bucketOff, rowptr, col);

    const int AB = NN / 8;  // 12500 (exact)

    // layer 0 aggregate
    aggregate_kernel<<<AB, 256, 0, stream>>>(hf8, As, Ad, rowptr, col, b0, abf, 1);
    // layer 1
    gemm_mfma_kernel<128><<<GB, 256, 0, stream>>>(abf, Wt1, as1, ad1, hf8, As, Ad);
    aggregate_kernel<<<AB, 256, 0, stream>>>(hf8, As, Ad, rowptr, col, b1, abf, 1);
    // layer 2
    gemm_mfma_kernel<128><<<GB, 256, 0, stream>>>(abf, Wt2, as2, ad2, hf8, As, Ad);
    aggregate_kernel<<<AB, 256, 0, stream>>>(hf8, As, Ad, rowptr, col, b2, abf, 0);

    // readout
    sum_kernel<<<256, 256, 0, stream>>>(abf, g);
    finalize_kernel<<<1, 128, 0, stream>>>(g, Wp, bp, out);
}